// Round 5
// baseline (818.060 us; speedup 1.0000x reference)
//
#include <hip/hip_runtime.h>

#define NN 100000
#define NE 1600000
constexpr float BN_EPS = 1e-5f;
constexpr float LRELU_SLOPE = 0.01f;
constexpr int SC_NB = (NN + 255) / 256;  // 391 scan blocks
constexpr int RANGE = 8192;              // node-range per histogram block (64 KB LDS)
constexpr int RNUM = (NN + RANGE - 1) / RANGE;  // 13
constexpr int SNUM = 40;                 // edge slices
constexpr int SLICE = NE / SNUM;         // 40000

// ---------------------------------------------------------------- phase A: per-(slice,range) histograms
// hd: row histogram (degree), hc: col histogram (CSR counts). No global atomics.
__global__ __launch_bounds__(256) void k_histA(const int* __restrict__ row,
                                               const int* __restrict__ col,
                                               int* __restrict__ PDd,
                                               int* __restrict__ PDc) {
  __shared__ int hd[RANGE];
  __shared__ int hc[RANGE];
  const int tid = threadIdx.x;
  const int s = blockIdx.x;
  const int r0 = blockIdx.y * RANGE;
  for (int i = tid; i < RANGE; i += 256) { hd[i] = 0; hc[i] = 0; }
  __syncthreads();
  const int e0 = s * SLICE;
  for (int i = tid; i < SLICE; i += 256) {
    const int rr = row[e0 + i];
    const int cc = col[e0 + i];
    const unsigned dr = (unsigned)(rr - r0);
    const unsigned dc = (unsigned)(cc - r0);
    if (dr < RANGE) atomicAdd(&hd[dr], 1);
    if (dc < RANGE) atomicAdd(&hc[dc], 1);
  }
  __syncthreads();
  const int nmax = min(RANGE, NN - r0);
  int* pd = PDd + (size_t)s * NN + r0;
  int* pc = PDc + (size_t)s * NN + r0;
  for (int i = tid; i < nmax; i += 256) {
    pd[i] = hd[i];
    pc[i] = hc[i];
  }
}

// ---------------------------------------------------------------- phase B: per-node slice-prefix + totals + dinv
__global__ __launch_bounds__(256) void k_histB(const int* __restrict__ PDd,
                                               const int* __restrict__ PDc,
                                               int* __restrict__ Bpart,
                                               int* __restrict__ cnt,
                                               float* __restrict__ dinv) {
  const int n = blockIdx.x * 256 + threadIdx.x;
  if (n >= NN) return;
  int run = 0, dsum = 0;
  for (int s = 0; s < SNUM; s++) {
    Bpart[(size_t)s * NN + n] = run;
    run += PDc[(size_t)s * NN + n];
    dsum += PDd[(size_t)s * NN + n];
  }
  cnt[n] = run;
  dinv[n] = dsum > 0 ? rsqrtf((float)dsum) : 0.0f;
}

// ---------------------------------------------------------------- 3-phase exclusive scan of cnt
__global__ __launch_bounds__(256) void k_scan_a(const int* __restrict__ cnt,
                                                int* __restrict__ bsum) {
  __shared__ int sh[256];
  const int tid = threadIdx.x;
  const int i = blockIdx.x * 256 + tid;
  sh[tid] = (i < NN) ? cnt[i] : 0;
  __syncthreads();
  for (int st = 128; st > 0; st >>= 1) {
    if (tid < st) sh[tid] += sh[tid + st];
    __syncthreads();
  }
  if (tid == 0) bsum[blockIdx.x] = sh[0];
}

__global__ __launch_bounds__(512) void k_scan_b(const int* __restrict__ bsum,
                                                int* __restrict__ boff) {
  __shared__ int sh[512];
  const int tid = threadIdx.x;
  const int v = (tid < SC_NB) ? bsum[tid] : 0;
  sh[tid] = v;
  __syncthreads();
  for (int off = 1; off < 512; off <<= 1) {
    int t = (tid >= off) ? sh[tid - off] : 0;
    __syncthreads();
    sh[tid] += t;
    __syncthreads();
  }
  if (tid < SC_NB) boff[tid] = sh[tid] - v;  // exclusive
}

__global__ __launch_bounds__(256) void k_scan_c(const int* __restrict__ cnt,
                                                const int* __restrict__ boff,
                                                int* __restrict__ ptr) {
  __shared__ int sh[256];
  const int tid = threadIdx.x;
  const int i = blockIdx.x * 256 + tid;
  const int v = (i < NN) ? cnt[i] : 0;
  sh[tid] = v;
  __syncthreads();
  for (int off = 1; off < 256; off <<= 1) {
    int t = (tid >= off) ? sh[tid - off] : 0;
    __syncthreads();
    sh[tid] += t;
    __syncthreads();
  }
  const int excl = sh[tid] - v + boff[blockIdx.x];
  if (i < NN) {
    ptr[i] = excl;
    if (i == NN - 1) ptr[NN] = excl + v;
  }
}

// ---------------------------------------------------------------- phase C: place edges (LDS cursors, no global atomics)
__global__ __launch_bounds__(256) void k_fill2(const int* __restrict__ row,
                                               const int* __restrict__ col,
                                               const float* __restrict__ dinv,
                                               const int* __restrict__ ptr,
                                               const int* __restrict__ Bpart,
                                               int2* __restrict__ eb) {
  __shared__ int cur[RANGE];
  __shared__ float dv[RANGE];
  const int tid = threadIdx.x;
  const int s = blockIdx.x;
  const int r0 = blockIdx.y * RANGE;
  const int nmax = min(RANGE, NN - r0);
  const int* bp = Bpart + (size_t)s * NN + r0;
  for (int i = tid; i < nmax; i += 256) {
    cur[i] = ptr[r0 + i] + bp[i];
    dv[i] = dinv[r0 + i];
  }
  __syncthreads();
  const int e0 = s * SLICE;
  for (int i = tid; i < SLICE; i += 256) {
    const int cc = col[e0 + i];
    const unsigned dc = (unsigned)(cc - r0);
    if (dc < RANGE) {
      const int rr = row[e0 + i];
      const int pos = atomicAdd(&cur[dc], 1);
      int2 rec;
      rec.x = rr;
      rec.y = __float_as_int(-dinv[rr] * dv[dc]);
      eb[pos] = rec;
    }
  }
}

// ---------------------------------------------------------------- prop (C=64): out[n] = [g[n] +] sum w_e p[src_e]
template <bool ADD>
__global__ __launch_bounds__(256) void k_prop64(const float* __restrict__ p,
                                                const int2* __restrict__ eb,
                                                const int* __restrict__ ptr,
                                                const float* __restrict__ g,
                                                float* __restrict__ out) {
  const int node = blockIdx.x * 16 + (threadIdx.x >> 4);
  const int lane = threadIdx.x & 15;
  if (node >= NN) return;
  const int b = ptr[node], e = ptr[node + 1];
  float4 acc0 = make_float4(0.f, 0.f, 0.f, 0.f);
  float4 acc1 = make_float4(0.f, 0.f, 0.f, 0.f);
  const float4* hp = reinterpret_cast<const float4*>(p) + lane;
  int j = b;
  for (; j + 2 <= e; j += 2) {
    const int2 e0 = eb[j], e1 = eb[j + 1];
    const float w0 = __int_as_float(e0.y), w1 = __int_as_float(e1.y);
    const float4 h0 = hp[(size_t)e0.x * 16];
    const float4 h1 = hp[(size_t)e1.x * 16];
    acc0.x += w0 * h0.x; acc0.y += w0 * h0.y; acc0.z += w0 * h0.z; acc0.w += w0 * h0.w;
    acc1.x += w1 * h1.x; acc1.y += w1 * h1.y; acc1.z += w1 * h1.z; acc1.w += w1 * h1.w;
  }
  if (j < e) {
    const int2 e0 = eb[j];
    const float w0 = __int_as_float(e0.y);
    const float4 h0 = hp[(size_t)e0.x * 16];
    acc0.x += w0 * h0.x; acc0.y += w0 * h0.y; acc0.z += w0 * h0.z; acc0.w += w0 * h0.w;
  }
  acc0.x += acc1.x; acc0.y += acc1.y; acc0.z += acc1.z; acc0.w += acc1.w;
  if (ADD) {
    const float4 gv = reinterpret_cast<const float4*>(g)[(size_t)node * 16 + lane];
    acc0.x += gv.x; acc0.y += gv.y; acc0.z += gv.z; acc0.w += gv.w;
  }
  reinterpret_cast<float4*>(out)[(size_t)node * 16 + lane] = acc0;
}

// ---------------------------------------------------------------- layer-1 conv: h1 = x@W0 + y@W1 + b
__global__ __launch_bounds__(512) void k_conv1(const float* __restrict__ x,
                                               const float* __restrict__ y,
                                               const float* __restrict__ W,
                                               const float* __restrict__ bias,
                                               float* __restrict__ out) {
  __shared__ float XA[64][65];
  __shared__ float XY[64][65];
  const int tid = threadIdx.x;
  const int lane = tid & 63;
  const int wv = __builtin_amdgcn_readfirstlane(tid >> 6);  // 0..7
  const int n0 = blockIdx.x * 64;
  for (int idx = tid; idx < 1024; idx += 512) {
    const int n = idx >> 4, k4 = idx & 15;
    int node = n0 + n;
    if (node >= NN) node = NN - 1;
    const float4 av = *reinterpret_cast<const float4*>(x + (size_t)node * 64 + k4 * 4);
    const float4 yv = *reinterpret_cast<const float4*>(y + (size_t)node * 64 + k4 * 4);
    float* da = &XA[n][k4 * 4];
    da[0] = av.x; da[1] = av.y; da[2] = av.z; da[3] = av.w;
    float* dy = &XY[n][k4 * 4];
    dy[0] = yv.x; dy[1] = yv.y; dy[2] = yv.z; dy[3] = yv.w;
  }
  __syncthreads();
  const int cw0 = wv * 16;
  const float* __restrict__ W0 = W + cw0;             // [64][128]
  const float* __restrict__ W1 = W + 64 * 128 + cw0;
  float acc[16];
#pragma unroll
  for (int j = 0; j < 16; j++) acc[j] = 0.f;
#pragma unroll 4
  for (int k = 0; k < 64; k++) {
    const float a = XA[lane][k];
    const float b = XY[lane][k];
#pragma unroll
    for (int j = 0; j < 16; j++)
      acc[j] += a * W0[(size_t)k * 128 + j] + b * W1[(size_t)k * 128 + j];
  }
  const int node = n0 + lane;
  if (node < NN) {
#pragma unroll
    for (int j = 0; j < 16; j += 4) {
      float4 o = make_float4(acc[j] + bias[cw0 + j], acc[j + 1] + bias[cw0 + j + 1],
                             acc[j + 2] + bias[cw0 + j + 2], acc[j + 3] + bias[cw0 + j + 3]);
      *reinterpret_cast<float4*>(out + (size_t)node * 128 + cw0 + j) = o;
    }
  }
}

// ---------------------------------------------------------------- dual GEMM: g = bn(h)@Wa + b, p = bn(h)@Wb
template <int Cin>
__global__ __launch_bounds__(512) void k_gemm_dual(const float* __restrict__ h,
                                                   const float* __restrict__ W,
                                                   const float* __restrict__ bias,
                                                   const float* __restrict__ scale,
                                                   const float* __restrict__ shift,
                                                   float* __restrict__ g,
                                                   float* __restrict__ p) {
  __shared__ float XA[64][Cin + 1];
  const int tid = threadIdx.x;
  const int lane = tid & 63;
  const int wv = __builtin_amdgcn_readfirstlane(tid >> 6);  // 0..7
  const int n0 = blockIdx.x * 64;
  constexpr int C4 = Cin / 4;
  for (int idx = tid; idx < 64 * C4; idx += 512) {
    const int n = idx / C4, k4 = idx % C4;
    int node = n0 + n;
    if (node >= NN) node = NN - 1;
    float4 v = *reinterpret_cast<const float4*>(h + (size_t)node * Cin + k4 * 4);
    const float4 sc = *reinterpret_cast<const float4*>(scale + k4 * 4);
    const float4 sh = *reinterpret_cast<const float4*>(shift + k4 * 4);
    v.x = sc.x * v.x + sh.x; v.y = sc.y * v.y + sh.y;
    v.z = sc.z * v.z + sh.z; v.w = sc.w * v.w + sh.w;
    v.x = v.x >= 0.f ? v.x : LRELU_SLOPE * v.x;
    v.y = v.y >= 0.f ? v.y : LRELU_SLOPE * v.y;
    v.z = v.z >= 0.f ? v.z : LRELU_SLOPE * v.z;
    v.w = v.w >= 0.f ? v.w : LRELU_SLOPE * v.w;
    float* d = &XA[n][k4 * 4];
    d[0] = v.x; d[1] = v.y; d[2] = v.z; d[3] = v.w;
  }
  __syncthreads();
  const int cw0 = wv * 8;
  const float* __restrict__ Wa = W + cw0;              // [Cin][64]
  const float* __restrict__ Wb = W + Cin * 64 + cw0;
  float ag[8], ap[8];
#pragma unroll
  for (int j = 0; j < 8; j++) { ag[j] = 0.f; ap[j] = 0.f; }
#pragma unroll 4
  for (int k = 0; k < Cin; k++) {
    const float a = XA[lane][k];
#pragma unroll
    for (int j = 0; j < 8; j++) {
      ag[j] += a * Wa[(size_t)k * 64 + j];
      ap[j] += a * Wb[(size_t)k * 64 + j];
    }
  }
  const int node = n0 + lane;
  if (node < NN) {
#pragma unroll
    for (int j = 0; j < 8; j += 4) {
      float4 og = make_float4(ag[j] + bias[cw0 + j], ag[j + 1] + bias[cw0 + j + 1],
                              ag[j + 2] + bias[cw0 + j + 2], ag[j + 3] + bias[cw0 + j + 3]);
      *reinterpret_cast<float4*>(g + (size_t)node * 64 + cw0 + j) = og;
      float4 op = make_float4(ap[j], ap[j + 1], ap[j + 2], ap[j + 3]);
      *reinterpret_cast<float4*>(p + (size_t)node * 64 + cw0 + j) = op;
    }
  }
}

// ---------------------------------------------------------------- BN stats (per-channel sum / sumsq)
template <int C>
__global__ __launch_bounds__(256) void k_bnstats(const float* __restrict__ h,
                                                 float* __restrict__ bnsum,
                                                 float* __restrict__ bnsq) {
  constexpr int RPB = 256 / C;
  constexpr int ROWS = 256;
  const int c = threadIdx.x % C;
  const int g = threadIdx.x / C;
  const int r0 = blockIdx.x * ROWS + g;
  const int rend = min(blockIdx.x * ROWS + ROWS, NN);
  float s = 0.f, sq = 0.f;
  for (int r = r0; r < rend; r += RPB) {
    float v = h[(size_t)r * C + c];
    s += v;
    sq += v * v;
  }
  __shared__ float ss[256], sg[256];
  ss[threadIdx.x] = s;
  sg[threadIdx.x] = sq;
  __syncthreads();
  for (int st = 128; st >= C; st >>= 1) {
    if (threadIdx.x < st) {
      ss[threadIdx.x] += ss[threadIdx.x + st];
      sg[threadIdx.x] += sg[threadIdx.x + st];
    }
    __syncthreads();
  }
  if (threadIdx.x < C) {
    atomicAdd(&bnsum[threadIdx.x], ss[threadIdx.x]);
    atomicAdd(&bnsq[threadIdx.x], sg[threadIdx.x]);
  }
}

template <int C>
__global__ void k_bnfin(const float* __restrict__ bnsum, const float* __restrict__ bnsq,
                        const float* __restrict__ gamma, const float* __restrict__ beta,
                        float* __restrict__ scale, float* __restrict__ shift) {
  int c = threadIdx.x;
  if (c < C) {
    float mean = bnsum[c] * (1.0f / NN);
    float var = bnsq[c] * (1.0f / NN) - mean * mean;
    float sc = gamma[c] * rsqrtf(var + BN_EPS);
    scale[c] = sc;
    shift[c] = beta[c] - mean * sc;
  }
}

// ----------------------------------------------------------------
extern "C" void kernel_launch(void* const* d_in, const int* in_sizes, int n_in,
                              void* d_out, int out_size, void* d_ws, size_t ws_size,
                              hipStream_t stream) {
  const float* x   = (const float*)d_in[0];
  const int*   ei  = (const int*)d_in[1];
  const int*   row = ei;
  const int*   col = ei + NE;
  const float* W1  = (const float*)d_in[2];
  const float* b1  = (const float*)d_in[3];
  const float* W2  = (const float*)d_in[4];
  const float* b2  = (const float*)d_in[5];
  const float* W3  = (const float*)d_in[6];
  const float* b3  = (const float*)d_in[7];
  const float* g1  = (const float*)d_in[8];
  const float* be1 = (const float*)d_in[9];
  const float* g2w = (const float*)d_in[10];
  const float* be2 = (const float*)d_in[11];
  float* out = (float*)d_out;

  char* ws = (char*)d_ws;
  size_t off = 0;
  auto alloc = [&](size_t bytes) -> void* {
    void* p = ws + off;
    off = (off + bytes + 255) & ~(size_t)255;
    return p;
  };

  // --- zeroed region (one tiny memset) ---
  float* bnsum1 = (float*)alloc(128 * 4);
  float* bnsq1  = (float*)alloc(128 * 4);
  float* bnsum2 = (float*)alloc(64 * 4);
  float* bnsq2  = (float*)alloc(64 * 4);
  const size_t zero_bytes = off;
  // --- rest ---
  float* dinv   = (float*)alloc(NN * 4);
  int*   cnt    = (int*)alloc(NN * 4);
  int*   ptr    = (int*)alloc((NN + 1) * 4);
  int*   bsum   = (int*)alloc(SC_NB * 4);
  int*   boff   = (int*)alloc(SC_NB * 4);
  int2*  eb     = (int2*)alloc((size_t)NE * 8);
  float* scale1 = (float*)alloc(128 * 4);
  float* shift1 = (float*)alloc(128 * 4);
  float* scale2 = (float*)alloc(64 * 4);
  float* shift2 = (float*)alloc(64 * 4);
  float* bufA   = (float*)alloc((size_t)NN * 64 * 4);   // y1, later g2
  float* bufB   = (float*)alloc((size_t)NN * 128 * 4);  // CSR-build scratch, then h1, later g3|p3
  float* bufC   = (float*)alloc((size_t)NN * 64 * 4);   // p2
  float* bufD   = (float*)alloc((size_t)NN * 64 * 4);   // h2

  // CSR-build scratch aliased onto bufB (h1 written only after build completes)
  int* PDd   = (int*)bufB;                              // [SNUM][NN]
  int* PDc   = PDd + (size_t)SNUM * NN;                 // [SNUM][NN]
  int* Bpart = PDc + (size_t)SNUM * NN;                 // [SNUM][NN]  (48 MB total <= 51.2 MB)

  float* y1 = bufA;
  float* h1 = bufB;
  float* gg2 = bufA;
  float* p2 = bufC;
  float* h2 = bufD;
  float* gg3 = bufB;
  float* p3 = bufB + (size_t)NN * 64;

  hipMemsetAsync(d_ws, 0, zero_bytes, stream);

  // graph prep: privatized counting sort (no global atomics)
  k_histA<<<dim3(SNUM, RNUM), 256, 0, stream>>>(row, col, PDd, PDc);
  k_histB<<<(NN + 255) / 256, 256, 0, stream>>>(PDd, PDc, Bpart, cnt, dinv);
  k_scan_a<<<SC_NB, 256, 0, stream>>>(cnt, bsum);
  k_scan_b<<<1, 512, 0, stream>>>(bsum, boff);
  k_scan_c<<<SC_NB, 256, 0, stream>>>(cnt, boff, ptr);
  k_fill2<<<dim3(SNUM, RNUM), 256, 0, stream>>>(row, col, dinv, ptr, Bpart, eb);

  const int gemmGrid = (NN + 63) / 64;
  const int propGrid = (NN * 16 + 255) / 256;

  // layer 1: y1 = L^ x ; h1 = x@W1[0] + y1@W1[1] + b1
  k_prop64<false><<<propGrid, 256, 0, stream>>>(x, eb, ptr, nullptr, y1);
  k_conv1<<<gemmGrid, 512, 0, stream>>>(x, y1, W1, b1, h1);
  k_bnstats<128><<<(NN + 255) / 256, 256, 0, stream>>>(h1, bnsum1, bnsq1);
  k_bnfin<128><<<1, 128, 0, stream>>>(bnsum1, bnsq1, g1, be1, scale1, shift1);

  // layer 2 (BN+lrelu fused into staging): g2 = bn(h1)@W2[0]+b2, p2 = bn(h1)@W2[1]; h2 = g2 + L^ p2
  k_gemm_dual<128><<<gemmGrid, 512, 0, stream>>>(h1, W2, b2, scale1, shift1, gg2, p2);
  k_prop64<true><<<propGrid, 256, 0, stream>>>(p2, eb, ptr, gg2, h2);
  k_bnstats<64><<<(NN + 255) / 256, 256, 0, stream>>>(h2, bnsum2, bnsq2);
  k_bnfin<64><<<1, 64, 0, stream>>>(bnsum2, bnsq2, g2w, be2, scale2, shift2);

  // layer 3: g3 = bn(h2)@W3[0]+b3, p3 = bn(h2)@W3[1]; out = g3 + L^ p3
  k_gemm_dual<64><<<gemmGrid, 512, 0, stream>>>(h2, W3, b3, scale2, shift2, gg3, p3);
  k_prop64<true><<<propGrid, 256, 0, stream>>>(p3, eb, ptr, gg3, out);
}

// Round 6
// 815.965 us; speedup vs baseline: 1.0026x; 1.0026x over previous
//
#include <hip/hip_runtime.h>

#define NN 100000
#define NE 1600000
constexpr float BN_EPS = 1e-5f;
constexpr float LRELU_SLOPE = 0.01f;
constexpr int SC_NB = (NN + 255) / 256;  // 391 scan blocks
constexpr int SNUM = 64;                 // edge slices (one block per slice)
constexpr int SLICE = NE / SNUM;         // 25000

// ---------------------------------------------------------------- phase 1: per-slice histograms
// Block s owns private rows PDd[s][*], PDc[s][*] -> workgroup-scope atomics stay in local XCD L2.
__global__ __launch_bounds__(1024) void k_hist(const int* __restrict__ row,
                                               const int* __restrict__ col,
                                               unsigned* __restrict__ PDd,
                                               unsigned* __restrict__ PDc) {
  const int s = blockIdx.x;
  const int tid = threadIdx.x;
  unsigned* pd = PDd + (size_t)s * NN;
  unsigned* pc = PDc + (size_t)s * NN;
  const int e0 = s * SLICE;
  for (int i = tid; i < SLICE; i += 1024) {
    const int rr = row[e0 + i];
    const int cc = col[e0 + i];
    __hip_atomic_fetch_add(&pd[rr], 1u, __ATOMIC_RELAXED, __HIP_MEMORY_SCOPE_WORKGROUP);
    __hip_atomic_fetch_add(&pc[cc], 1u, __ATOMIC_RELAXED, __HIP_MEMORY_SCOPE_WORKGROUP);
  }
}

// ---------------------------------------------------------------- phase 2: per-node slice prefix + totals + dinv
__global__ __launch_bounds__(256) void k_csrmid(const unsigned* __restrict__ PDd,
                                                const unsigned* __restrict__ PDc,
                                                int* __restrict__ Bpart,
                                                int* __restrict__ cnt,
                                                float* __restrict__ dinv) {
  const int n = blockIdx.x * 256 + threadIdx.x;
  if (n >= NN) return;
  unsigned run = 0, dsum = 0;
  for (int s = 0; s < SNUM; s++) {
    Bpart[(size_t)s * NN + n] = (int)run;
    run += PDc[(size_t)s * NN + n];
    dsum += PDd[(size_t)s * NN + n];
  }
  cnt[n] = (int)run;
  dinv[n] = dsum > 0 ? rsqrtf((float)dsum) : 0.0f;
}

// ---------------------------------------------------------------- 3-phase exclusive scan of cnt
__global__ __launch_bounds__(256) void k_scan_a(const int* __restrict__ cnt,
                                                int* __restrict__ bsum) {
  __shared__ int sh[256];
  const int tid = threadIdx.x;
  const int i = blockIdx.x * 256 + tid;
  sh[tid] = (i < NN) ? cnt[i] : 0;
  __syncthreads();
  for (int st = 128; st > 0; st >>= 1) {
    if (tid < st) sh[tid] += sh[tid + st];
    __syncthreads();
  }
  if (tid == 0) bsum[blockIdx.x] = sh[0];
}

__global__ __launch_bounds__(512) void k_scan_b(const int* __restrict__ bsum,
                                                int* __restrict__ boff) {
  __shared__ int sh[512];
  const int tid = threadIdx.x;
  const int v = (tid < SC_NB) ? bsum[tid] : 0;
  sh[tid] = v;
  __syncthreads();
  for (int off = 1; off < 512; off <<= 1) {
    int t = (tid >= off) ? sh[tid - off] : 0;
    __syncthreads();
    sh[tid] += t;
    __syncthreads();
  }
  if (tid < SC_NB) boff[tid] = sh[tid] - v;  // exclusive
}

__global__ __launch_bounds__(256) void k_scan_c(const int* __restrict__ cnt,
                                                const int* __restrict__ boff,
                                                int* __restrict__ ptr) {
  __shared__ int sh[256];
  const int tid = threadIdx.x;
  const int i = blockIdx.x * 256 + tid;
  const int v = (i < NN) ? cnt[i] : 0;
  sh[tid] = v;
  __syncthreads();
  for (int off = 1; off < 256; off <<= 1) {
    int t = (tid >= off) ? sh[tid - off] : 0;
    __syncthreads();
    sh[tid] += t;
    __syncthreads();
  }
  const int excl = sh[tid] - v + boff[blockIdx.x];
  if (i < NN) {
    ptr[i] = excl;
    if (i == NN - 1) ptr[NN] = excl + v;
  }
}

// ---------------------------------------------------------------- phase 3: place edges (src-only records)
// pos = ptr[c] + Bpart[s][c]++ ; Bpart row is block-private -> wg-scope atomic (L2-local).
__global__ __launch_bounds__(1024) void k_fill3(const int* __restrict__ row,
                                                const int* __restrict__ col,
                                                const int* __restrict__ ptr,
                                                int* __restrict__ Bpart,
                                                int* __restrict__ eb) {
  const int s = blockIdx.x;
  const int tid = threadIdx.x;
  int* bp = Bpart + (size_t)s * NN;
  const int e0 = s * SLICE;
  for (int i = tid; i < SLICE; i += 1024) {
    const int rr = row[e0 + i];
    const int cc = col[e0 + i];
    const int ofs = __hip_atomic_fetch_add(&bp[cc], 1, __ATOMIC_RELAXED, __HIP_MEMORY_SCOPE_WORKGROUP);
    eb[ptr[cc] + ofs] = rr;
  }
}

// ---------------------------------------------------------------- xs = dinv * x (layer-1 pre-scale)
__global__ __launch_bounds__(256) void k_scale(const float* __restrict__ x,
                                               const float* __restrict__ dinv,
                                               float* __restrict__ xs) {
  const size_t i = (size_t)blockIdx.x * 256 + threadIdx.x;  // float4 index, grid exact
  const int n = (int)(i >> 4);
  float4 v = reinterpret_cast<const float4*>(x)[i];
  const float d = dinv[n];
  v.x *= d; v.y *= d; v.z *= d; v.w *= d;
  reinterpret_cast<float4*>(xs)[i] = v;
}

// ---------------------------------------------------------------- prop: acc[n] = sum_{e: col=n} p[src_e]
// ADD variant: out = g - dinv[n]*acc (p must be pre-scaled by dinv). non-ADD: out = raw acc.
template <bool ADD>
__global__ __launch_bounds__(256) void k_prop64(const float* __restrict__ p,
                                                const int* __restrict__ eb,
                                                const int* __restrict__ ptr,
                                                const float* __restrict__ g,
                                                const float* __restrict__ dinv,
                                                float* __restrict__ out) {
  const int node = blockIdx.x * 16 + (threadIdx.x >> 4);
  const int lane = threadIdx.x & 15;
  if (node >= NN) return;
  const int b = ptr[node], e = ptr[node + 1];
  float4 acc0 = make_float4(0.f, 0.f, 0.f, 0.f);
  float4 acc1 = make_float4(0.f, 0.f, 0.f, 0.f);
  const float4* hp = reinterpret_cast<const float4*>(p) + lane;
  int j = b;
  for (; j + 2 <= e; j += 2) {
    const int s0 = eb[j], s1 = eb[j + 1];
    const float4 h0 = hp[(size_t)s0 * 16];
    const float4 h1 = hp[(size_t)s1 * 16];
    acc0.x += h0.x; acc0.y += h0.y; acc0.z += h0.z; acc0.w += h0.w;
    acc1.x += h1.x; acc1.y += h1.y; acc1.z += h1.z; acc1.w += h1.w;
  }
  if (j < e) {
    const int s0 = eb[j];
    const float4 h0 = hp[(size_t)s0 * 16];
    acc0.x += h0.x; acc0.y += h0.y; acc0.z += h0.z; acc0.w += h0.w;
  }
  acc0.x += acc1.x; acc0.y += acc1.y; acc0.z += acc1.z; acc0.w += acc1.w;
  if (ADD) {
    const float dn = dinv[node];
    const float4 gv = reinterpret_cast<const float4*>(g)[(size_t)node * 16 + lane];
    acc0.x = gv.x - dn * acc0.x;
    acc0.y = gv.y - dn * acc0.y;
    acc0.z = gv.z - dn * acc0.z;
    acc0.w = gv.w - dn * acc0.w;
  }
  reinterpret_cast<float4*>(out)[(size_t)node * 16 + lane] = acc0;
}

// ---------------------------------------------------------------- layer-1 conv: h1 = x@W0 + (-dinv*y)@W1 + b
__global__ __launch_bounds__(512) void k_conv1(const float* __restrict__ x,
                                               const float* __restrict__ y,
                                               const float* __restrict__ dinv,
                                               const float* __restrict__ W,
                                               const float* __restrict__ bias,
                                               float* __restrict__ out) {
  __shared__ float XA[64][65];
  __shared__ float XY[64][65];
  const int tid = threadIdx.x;
  const int lane = tid & 63;
  const int wv = __builtin_amdgcn_readfirstlane(tid >> 6);  // 0..7
  const int n0 = blockIdx.x * 64;
  for (int idx = tid; idx < 1024; idx += 512) {
    const int n = idx >> 4, k4 = idx & 15;
    int node = n0 + n;
    if (node >= NN) node = NN - 1;
    const float4 av = *reinterpret_cast<const float4*>(x + (size_t)node * 64 + k4 * 4);
    float4 yv = *reinterpret_cast<const float4*>(y + (size_t)node * 64 + k4 * 4);
    const float dn = -dinv[node];
    yv.x *= dn; yv.y *= dn; yv.z *= dn; yv.w *= dn;
    float* da = &XA[n][k4 * 4];
    da[0] = av.x; da[1] = av.y; da[2] = av.z; da[3] = av.w;
    float* dy = &XY[n][k4 * 4];
    dy[0] = yv.x; dy[1] = yv.y; dy[2] = yv.z; dy[3] = yv.w;
  }
  __syncthreads();
  const int cw0 = wv * 16;
  const float* __restrict__ W0 = W + cw0;             // [64][128]
  const float* __restrict__ W1 = W + 64 * 128 + cw0;
  float acc[16];
#pragma unroll
  for (int j = 0; j < 16; j++) acc[j] = 0.f;
#pragma unroll 4
  for (int k = 0; k < 64; k++) {
    const float a = XA[lane][k];
    const float b = XY[lane][k];
#pragma unroll
    for (int j = 0; j < 16; j++)
      acc[j] += a * W0[(size_t)k * 128 + j] + b * W1[(size_t)k * 128 + j];
  }
  const int node = n0 + lane;
  if (node < NN) {
#pragma unroll
    for (int j = 0; j < 16; j += 4) {
      float4 o = make_float4(acc[j] + bias[cw0 + j], acc[j + 1] + bias[cw0 + j + 1],
                             acc[j + 2] + bias[cw0 + j + 2], acc[j + 3] + bias[cw0 + j + 3]);
      *reinterpret_cast<float4*>(out + (size_t)node * 128 + cw0 + j) = o;
    }
  }
}

// ---------------------------------------------------------------- dual GEMM: g = bn(h)@Wa + b, p = dinv * (bn(h)@Wb)
template <int Cin>
__global__ __launch_bounds__(512) void k_gemm_dual(const float* __restrict__ h,
                                                   const float* __restrict__ W,
                                                   const float* __restrict__ bias,
                                                   const float* __restrict__ scale,
                                                   const float* __restrict__ shift,
                                                   const float* __restrict__ dinv,
                                                   float* __restrict__ g,
                                                   float* __restrict__ p) {
  __shared__ float XA[64][Cin + 1];
  const int tid = threadIdx.x;
  const int lane = tid & 63;
  const int wv = __builtin_amdgcn_readfirstlane(tid >> 6);  // 0..7
  const int n0 = blockIdx.x * 64;
  constexpr int C4 = Cin / 4;
  for (int idx = tid; idx < 64 * C4; idx += 512) {
    const int n = idx / C4, k4 = idx % C4;
    int node = n0 + n;
    if (node >= NN) node = NN - 1;
    float4 v = *reinterpret_cast<const float4*>(h + (size_t)node * Cin + k4 * 4);
    const float4 sc = *reinterpret_cast<const float4*>(scale + k4 * 4);
    const float4 sh = *reinterpret_cast<const float4*>(shift + k4 * 4);
    v.x = sc.x * v.x + sh.x; v.y = sc.y * v.y + sh.y;
    v.z = sc.z * v.z + sh.z; v.w = sc.w * v.w + sh.w;
    v.x = v.x >= 0.f ? v.x : LRELU_SLOPE * v.x;
    v.y = v.y >= 0.f ? v.y : LRELU_SLOPE * v.y;
    v.z = v.z >= 0.f ? v.z : LRELU_SLOPE * v.z;
    v.w = v.w >= 0.f ? v.w : LRELU_SLOPE * v.w;
    float* d = &XA[n][k4 * 4];
    d[0] = v.x; d[1] = v.y; d[2] = v.z; d[3] = v.w;
  }
  __syncthreads();
  const int cw0 = wv * 8;
  const float* __restrict__ Wa = W + cw0;              // [Cin][64]
  const float* __restrict__ Wb = W + Cin * 64 + cw0;
  float ag[8], ap[8];
#pragma unroll
  for (int j = 0; j < 8; j++) { ag[j] = 0.f; ap[j] = 0.f; }
#pragma unroll 4
  for (int k = 0; k < Cin; k++) {
    const float a = XA[lane][k];
#pragma unroll
    for (int j = 0; j < 8; j++) {
      ag[j] += a * Wa[(size_t)k * 64 + j];
      ap[j] += a * Wb[(size_t)k * 64 + j];
    }
  }
  const int node = n0 + lane;
  if (node < NN) {
    const float dn = dinv[node];
#pragma unroll
    for (int j = 0; j < 8; j += 4) {
      float4 og = make_float4(ag[j] + bias[cw0 + j], ag[j + 1] + bias[cw0 + j + 1],
                              ag[j + 2] + bias[cw0 + j + 2], ag[j + 3] + bias[cw0 + j + 3]);
      *reinterpret_cast<float4*>(g + (size_t)node * 64 + cw0 + j) = og;
      float4 op = make_float4(ap[j] * dn, ap[j + 1] * dn, ap[j + 2] * dn, ap[j + 3] * dn);
      *reinterpret_cast<float4*>(p + (size_t)node * 64 + cw0 + j) = op;
    }
  }
}

// ---------------------------------------------------------------- BN stats (per-channel sum / sumsq)
template <int C>
__global__ __launch_bounds__(256) void k_bnstats(const float* __restrict__ h,
                                                 float* __restrict__ bnsum,
                                                 float* __restrict__ bnsq) {
  constexpr int RPB = 256 / C;
  constexpr int ROWS = 256;
  const int c = threadIdx.x % C;
  const int g = threadIdx.x / C;
  const int r0 = blockIdx.x * ROWS + g;
  const int rend = min(blockIdx.x * ROWS + ROWS, NN);
  float s = 0.f, sq = 0.f;
  for (int r = r0; r < rend; r += RPB) {
    float v = h[(size_t)r * C + c];
    s += v;
    sq += v * v;
  }
  __shared__ float ss[256], sg[256];
  ss[threadIdx.x] = s;
  sg[threadIdx.x] = sq;
  __syncthreads();
  for (int st = 128; st >= C; st >>= 1) {
    if (threadIdx.x < st) {
      ss[threadIdx.x] += ss[threadIdx.x + st];
      sg[threadIdx.x] += sg[threadIdx.x + st];
    }
    __syncthreads();
  }
  if (threadIdx.x < C) {
    atomicAdd(&bnsum[threadIdx.x], ss[threadIdx.x]);
    atomicAdd(&bnsq[threadIdx.x], sg[threadIdx.x]);
  }
}

template <int C>
__global__ void k_bnfin(const float* __restrict__ bnsum, const float* __restrict__ bnsq,
                        const float* __restrict__ gamma, const float* __restrict__ beta,
                        float* __restrict__ scale, float* __restrict__ shift) {
  int c = threadIdx.x;
  if (c < C) {
    float mean = bnsum[c] * (1.0f / NN);
    float var = bnsq[c] * (1.0f / NN) - mean * mean;
    float sc = gamma[c] * rsqrtf(var + BN_EPS);
    scale[c] = sc;
    shift[c] = beta[c] - mean * sc;
  }
}

// ----------------------------------------------------------------
extern "C" void kernel_launch(void* const* d_in, const int* in_sizes, int n_in,
                              void* d_out, int out_size, void* d_ws, size_t ws_size,
                              hipStream_t stream) {
  const float* x   = (const float*)d_in[0];
  const int*   ei  = (const int*)d_in[1];
  const int*   row = ei;
  const int*   col = ei + NE;
  const float* W1  = (const float*)d_in[2];
  const float* b1  = (const float*)d_in[3];
  const float* W2  = (const float*)d_in[4];
  const float* b2  = (const float*)d_in[5];
  const float* W3  = (const float*)d_in[6];
  const float* b3  = (const float*)d_in[7];
  const float* g1  = (const float*)d_in[8];
  const float* be1 = (const float*)d_in[9];
  const float* g2w = (const float*)d_in[10];
  const float* be2 = (const float*)d_in[11];
  float* out = (float*)d_out;

  char* ws = (char*)d_ws;
  size_t off = 0;
  auto alloc = [&](size_t bytes) -> void* {
    void* p = ws + off;
    off = (off + bytes + 255) & ~(size_t)255;
    return p;
  };

  // --- zeroed region (one tiny memset) ---
  float* bnsum1 = (float*)alloc(128 * 4);
  float* bnsq1  = (float*)alloc(128 * 4);
  float* bnsum2 = (float*)alloc(64 * 4);
  float* bnsq2  = (float*)alloc(64 * 4);
  const size_t zero_bytes = off;
  // --- rest ---
  float* dinv   = (float*)alloc(NN * 4);
  int*   cnt    = (int*)alloc(NN * 4);
  int*   ptr    = (int*)alloc((NN + 1) * 4);
  int*   bsum   = (int*)alloc(SC_NB * 4);
  int*   boff   = (int*)alloc(SC_NB * 4);
  int*   eb     = (int*)alloc((size_t)NE * 4);
  float* scale1 = (float*)alloc(128 * 4);
  float* shift1 = (float*)alloc(128 * 4);
  float* scale2 = (float*)alloc(64 * 4);
  float* shift2 = (float*)alloc(64 * 4);
  float* bufA   = (float*)alloc((size_t)NN * 64 * 4);   // y1, later g2
  float* bufB   = (float*)alloc((size_t)NN * 128 * 4);  // PDd|PDc, then h1, later g3|p3
  float* bufC   = (float*)alloc((size_t)NN * 64 * 4);   // Bpart, then xs, later p2
  float* bufD   = (float*)alloc((size_t)NN * 64 * 4);   // h2

  // build scratch aliases
  unsigned* PDd   = (unsigned*)bufB;                    // [SNUM][NN]
  unsigned* PDc   = PDd + (size_t)SNUM * NN;            // [SNUM][NN]
  int*      Bpart = (int*)bufC;                         // [SNUM][NN]

  float* y1  = bufA;
  float* xs  = bufC;
  float* h1  = bufB;
  float* gg2 = bufA;
  float* p2  = bufC;
  float* h2  = bufD;
  float* gg3 = bufB;
  float* p3  = bufB + (size_t)NN * 64;

  hipMemsetAsync(d_ws, 0, zero_bytes, stream);
  hipMemsetAsync(PDd, 0, (size_t)2 * SNUM * NN * 4, stream);  // 51.2 MB

  // graph prep: counting sort with XCD-local (workgroup-scope) atomics
  k_hist<<<SNUM, 1024, 0, stream>>>(row, col, PDd, PDc);
  k_csrmid<<<(NN + 255) / 256, 256, 0, stream>>>(PDd, PDc, Bpart, cnt, dinv);
  k_scan_a<<<SC_NB, 256, 0, stream>>>(cnt, bsum);
  k_scan_b<<<1, 512, 0, stream>>>(bsum, boff);
  k_scan_c<<<SC_NB, 256, 0, stream>>>(cnt, boff, ptr);
  k_fill3<<<SNUM, 1024, 0, stream>>>(row, col, ptr, Bpart, eb);

  const int gemmGrid = (NN + 63) / 64;
  const int propGrid = (NN * 16 + 255) / 256;

  // layer 1: xs = dinv*x ; y1 = sum_gather(xs) ; h1 = x@W1[0] + (-dinv*y1)@W1[1] + b1
  k_scale<<<NN * 16 / 256, 256, 0, stream>>>(x, dinv, xs);
  k_prop64<false><<<propGrid, 256, 0, stream>>>(xs, eb, ptr, nullptr, nullptr, y1);
  k_conv1<<<gemmGrid, 512, 0, stream>>>(x, y1, dinv, W1, b1, h1);
  k_bnstats<128><<<(NN + 255) / 256, 256, 0, stream>>>(h1, bnsum1, bnsq1);
  k_bnfin<128><<<1, 128, 0, stream>>>(bnsum1, bnsq1, g1, be1, scale1, shift1);

  // layer 2: g2 = bn(h1)@W2[0]+b2, p2 = dinv*(bn(h1)@W2[1]); h2 = g2 - dinv*sum_gather(p2)
  k_gemm_dual<128><<<gemmGrid, 512, 0, stream>>>(h1, W2, b2, scale1, shift1, dinv, gg2, p2);
  k_prop64<true><<<propGrid, 256, 0, stream>>>(p2, eb, ptr, gg2, dinv, h2);
  k_bnstats<64><<<(NN + 255) / 256, 256, 0, stream>>>(h2, bnsum2, bnsq2);
  k_bnfin<64><<<1, 64, 0, stream>>>(bnsum2, bnsq2, g2w, be2, scale2, shift2);

  // layer 3: g3 = bn(h2)@W3[0]+b3, p3 = dinv*(bn(h2)@W3[1]); out = g3 - dinv*sum_gather(p3)
  k_gemm_dual<64><<<gemmGrid, 512, 0, stream>>>(h2, W3, b3, scale2, shift2, dinv, gg3, p3);
  k_prop64<true><<<propGrid, 256, 0, stream>>>(p3, eb, ptr, gg3, dinv, out);
}

// Round 7
// 582.119 us; speedup vs baseline: 1.4053x; 1.4017x over previous
//
#include <hip/hip_runtime.h>

#define NN 100000
#define NE 1600000
constexpr float BN_EPS = 1e-5f;
constexpr float LRELU_SLOPE = 0.01f;
constexpr int SC_NB = (NN + 255) / 256;  // 391 scan blocks
constexpr int RSH = 13;                  // range shift (8192)
constexpr int RB = 1 << RSH;             // 8192 nodes per range-bucket
constexpr int NR = (NN + RB - 1) / RB;   // 13 buckets
constexpr int SB = 8;                    // slices per bucket (phase 2/4)
constexpr int CAP = 163840;              // bucket capacity (mean 131k, sigma ~350)
constexpr int PBLK = 400;                // partition blocks
constexpr int PCHUNK = NE / PBLK;        // 4000 edges per partition block

// ---------------------------------------------------------------- P1: partition edges by col-range (and row values by row-range)
// Only 26 global atomics per block; per-edge work is LDS atomics + contiguous stream writes.
__global__ __launch_bounds__(256) void k_part(const int* __restrict__ row,
                                              const int* __restrict__ col,
                                              int* __restrict__ colCnt,   // [NR] zeroed
                                              int* __restrict__ rowCnt,   // [NR] zeroed
                                              int2* __restrict__ colbuf,  // [NR][CAP] (src,col)
                                              int* __restrict__ rowbuf) { // [NR][CAP] src values
  __shared__ int cntc[NR], cntr[NR];
  const int tid = threadIdx.x;
  const int e0 = blockIdx.x * PCHUNK;
  if (tid < NR) { cntc[tid] = 0; cntr[tid] = 0; }
  __syncthreads();
  for (int i = tid; i < PCHUNK; i += 256) {
    atomicAdd(&cntc[col[e0 + i] >> RSH], 1);
    atomicAdd(&cntr[row[e0 + i] >> RSH], 1);
  }
  __syncthreads();
  if (tid < NR) {
    cntc[tid] = atomicAdd(&colCnt[tid], cntc[tid]);            // base in col-bucket
  } else if (tid >= 64 && tid < 64 + NR) {
    const int b = tid - 64;
    cntr[b] = atomicAdd(&rowCnt[b], cntr[b]);                  // base in row-bucket
  }
  __syncthreads();
  for (int i = tid; i < PCHUNK; i += 256) {
    const int r = row[e0 + i];
    const int c = col[e0 + i];
    const int bc = c >> RSH;
    const int pc = atomicAdd(&cntc[bc], 1);
    colbuf[(size_t)bc * CAP + pc] = make_int2(r, c);
    const int br = r >> RSH;
    const int pr = atomicAdd(&cntr[br], 1);
    rowbuf[(size_t)br * CAP + pr] = r;
  }
}

// ---------------------------------------------------------------- P2: per-(bucket,slice) LDS histogram
// z=0: col histogram from colbuf -> PDc ; z=1: row-value histogram from rowbuf -> PDd
__global__ __launch_bounds__(1024) void k_hist2(const int2* __restrict__ colbuf,
                                                const int* __restrict__ rowbuf,
                                                const int* __restrict__ colCnt,
                                                const int* __restrict__ rowCnt,
                                                int* __restrict__ PDc,   // [NR][SB][RB]
                                                int* __restrict__ PDd) { // [NR][SB][RB]
  __shared__ int h[RB];
  const int tid = threadIdx.x;
  const int b = blockIdx.x, s = blockIdx.y, z = blockIdx.z;
  for (int i = tid; i < RB; i += 1024) h[i] = 0;
  __syncthreads();
  const int base = b << RSH;
  const int len = z ? rowCnt[b] : colCnt[b];
  const int sl = (len + SB - 1) / SB;
  const int st = s * sl;
  const int en = min(st + sl, len);
  if (z == 0) {
    const int2* cb = colbuf + (size_t)b * CAP;
    for (int i = st + tid; i < en; i += 1024)
      atomicAdd(&h[cb[i].y - base], 1);
  } else {
    const int* rb = rowbuf + (size_t)b * CAP;
    for (int i = st + tid; i < en; i += 1024)
      atomicAdd(&h[rb[i] - base], 1);
  }
  __syncthreads();
  int* pd = (z ? PDd : PDc) + ((size_t)b * SB + s) * RB;
  for (int i = tid; i < RB; i += 1024) pd[i] = h[i];
}

// ---------------------------------------------------------------- P3: per-node slice prefix + totals + dinv
__global__ __launch_bounds__(256) void k_csrmid2(const int* __restrict__ PDc,
                                                 const int* __restrict__ PDd,
                                                 int* __restrict__ Bpart,  // [SB][NN]
                                                 int* __restrict__ cnt,
                                                 float* __restrict__ dinv) {
  const int n = blockIdx.x * 256 + threadIdx.x;
  if (n >= NN) return;
  const int b = n >> RSH, o = n & (RB - 1);
  int run = 0, dsum = 0;
#pragma unroll
  for (int s = 0; s < SB; s++) {
    Bpart[(size_t)s * NN + n] = run;
    run += PDc[((size_t)b * SB + s) * RB + o];
    dsum += PDd[((size_t)b * SB + s) * RB + o];
  }
  cnt[n] = run;
  dinv[n] = dsum > 0 ? rsqrtf((float)dsum) : 0.0f;
}

// ---------------------------------------------------------------- 3-phase exclusive scan of cnt
__global__ __launch_bounds__(256) void k_scan_a(const int* __restrict__ cnt,
                                                int* __restrict__ bsum) {
  __shared__ int sh[256];
  const int tid = threadIdx.x;
  const int i = blockIdx.x * 256 + tid;
  sh[tid] = (i < NN) ? cnt[i] : 0;
  __syncthreads();
  for (int st = 128; st > 0; st >>= 1) {
    if (tid < st) sh[tid] += sh[tid + st];
    __syncthreads();
  }
  if (tid == 0) bsum[blockIdx.x] = sh[0];
}

__global__ __launch_bounds__(512) void k_scan_b(const int* __restrict__ bsum,
                                                int* __restrict__ boff) {
  __shared__ int sh[512];
  const int tid = threadIdx.x;
  const int v = (tid < SC_NB) ? bsum[tid] : 0;
  sh[tid] = v;
  __syncthreads();
  for (int off = 1; off < 512; off <<= 1) {
    int t = (tid >= off) ? sh[tid - off] : 0;
    __syncthreads();
    sh[tid] += t;
    __syncthreads();
  }
  if (tid < SC_NB) boff[tid] = sh[tid] - v;  // exclusive
}

__global__ __launch_bounds__(256) void k_scan_c(const int* __restrict__ cnt,
                                                const int* __restrict__ boff,
                                                int* __restrict__ ptr) {
  __shared__ int sh[256];
  const int tid = threadIdx.x;
  const int i = blockIdx.x * 256 + tid;
  const int v = (i < NN) ? cnt[i] : 0;
  sh[tid] = v;
  __syncthreads();
  for (int off = 1; off < 256; off <<= 1) {
    int t = (tid >= off) ? sh[tid - off] : 0;
    __syncthreads();
    sh[tid] += t;
    __syncthreads();
  }
  const int excl = sh[tid] - v + boff[blockIdx.x];
  if (i < NN) {
    ptr[i] = excl;
    if (i == NN - 1) ptr[NN] = excl + v;
  }
}

// ---------------------------------------------------------------- P4: place edges via LDS cursors (bucket-local reads only)
__global__ __launch_bounds__(1024) void k_fill4(const int2* __restrict__ colbuf,
                                                const int* __restrict__ colCnt,
                                                const int* __restrict__ ptr,
                                                const int* __restrict__ Bpart,
                                                int* __restrict__ eb) {
  __shared__ int cur[RB];
  const int tid = threadIdx.x;
  const int b = blockIdx.x, s = blockIdx.y;
  const int base = b << RSH;
  const int nmax = min(RB, NN - base);
  const int* bp = Bpart + (size_t)s * NN + base;
  for (int i = tid; i < nmax; i += 1024) cur[i] = ptr[base + i] + bp[i];
  __syncthreads();
  const int len = colCnt[b];
  const int sl = (len + SB - 1) / SB;
  const int st = s * sl;
  const int en = min(st + sl, len);
  const int2* cb = colbuf + (size_t)b * CAP;
  for (int i = st + tid; i < en; i += 1024) {
    const int2 rec = cb[i];
    const int pos = atomicAdd(&cur[rec.y - base], 1);
    eb[pos] = rec.x;
  }
}

// ---------------------------------------------------------------- xs = dinv * x (layer-1 pre-scale)
__global__ __launch_bounds__(256) void k_scale(const float* __restrict__ x,
                                               const float* __restrict__ dinv,
                                               float* __restrict__ xs) {
  const size_t i = (size_t)blockIdx.x * 256 + threadIdx.x;  // float4 index, grid exact
  const int n = (int)(i >> 4);
  float4 v = reinterpret_cast<const float4*>(x)[i];
  const float d = dinv[n];
  v.x *= d; v.y *= d; v.z *= d; v.w *= d;
  reinterpret_cast<float4*>(xs)[i] = v;
}

// ---------------------------------------------------------------- prop: acc[n] = sum_{e: col=n} p[src_e]
// ADD: out = g - dinv[n]*acc (p pre-scaled by dinv). non-ADD: raw acc. Unrolled x4 for MLP depth.
template <bool ADD>
__global__ __launch_bounds__(256) void k_prop64(const float* __restrict__ p,
                                                const int* __restrict__ eb,
                                                const int* __restrict__ ptr,
                                                const float* __restrict__ g,
                                                const float* __restrict__ dinv,
                                                float* __restrict__ out) {
  const int node = blockIdx.x * 16 + (threadIdx.x >> 4);
  const int lane = threadIdx.x & 15;
  if (node >= NN) return;
  const int b = ptr[node], e = ptr[node + 1];
  float4 a0 = make_float4(0.f, 0.f, 0.f, 0.f);
  float4 a1 = make_float4(0.f, 0.f, 0.f, 0.f);
  float4 a2 = make_float4(0.f, 0.f, 0.f, 0.f);
  float4 a3 = make_float4(0.f, 0.f, 0.f, 0.f);
  const float4* hp = reinterpret_cast<const float4*>(p) + lane;
  int j = b;
  for (; j + 4 <= e; j += 4) {
    const int s0 = eb[j], s1 = eb[j + 1], s2 = eb[j + 2], s3 = eb[j + 3];
    const float4 h0 = hp[(size_t)s0 * 16];
    const float4 h1 = hp[(size_t)s1 * 16];
    const float4 h2 = hp[(size_t)s2 * 16];
    const float4 h3 = hp[(size_t)s3 * 16];
    a0.x += h0.x; a0.y += h0.y; a0.z += h0.z; a0.w += h0.w;
    a1.x += h1.x; a1.y += h1.y; a1.z += h1.z; a1.w += h1.w;
    a2.x += h2.x; a2.y += h2.y; a2.z += h2.z; a2.w += h2.w;
    a3.x += h3.x; a3.y += h3.y; a3.z += h3.z; a3.w += h3.w;
  }
  for (; j + 2 <= e; j += 2) {
    const int s0 = eb[j], s1 = eb[j + 1];
    const float4 h0 = hp[(size_t)s0 * 16];
    const float4 h1 = hp[(size_t)s1 * 16];
    a0.x += h0.x; a0.y += h0.y; a0.z += h0.z; a0.w += h0.w;
    a1.x += h1.x; a1.y += h1.y; a1.z += h1.z; a1.w += h1.w;
  }
  if (j < e) {
    const float4 h0 = hp[(size_t)eb[j] * 16];
    a0.x += h0.x; a0.y += h0.y; a0.z += h0.z; a0.w += h0.w;
  }
  a0.x += a1.x + a2.x + a3.x;
  a0.y += a1.y + a2.y + a3.y;
  a0.z += a1.z + a2.z + a3.z;
  a0.w += a1.w + a2.w + a3.w;
  if (ADD) {
    const float dn = dinv[node];
    const float4 gv = reinterpret_cast<const float4*>(g)[(size_t)node * 16 + lane];
    a0.x = gv.x - dn * a0.x;
    a0.y = gv.y - dn * a0.y;
    a0.z = gv.z - dn * a0.z;
    a0.w = gv.w - dn * a0.w;
  }
  reinterpret_cast<float4*>(out)[(size_t)node * 16 + lane] = a0;
}

// ---------------------------------------------------------------- layer-1 conv: h1 = x@W0 + (-dinv*y)@W1 + b
__global__ __launch_bounds__(512) void k_conv1(const float* __restrict__ x,
                                               const float* __restrict__ y,
                                               const float* __restrict__ dinv,
                                               const float* __restrict__ W,
                                               const float* __restrict__ bias,
                                               float* __restrict__ out) {
  __shared__ float XA[64][65];
  __shared__ float XY[64][65];
  const int tid = threadIdx.x;
  const int lane = tid & 63;
  const int wv = __builtin_amdgcn_readfirstlane(tid >> 6);  // 0..7
  const int n0 = blockIdx.x * 64;
  for (int idx = tid; idx < 1024; idx += 512) {
    const int n = idx >> 4, k4 = idx & 15;
    int node = n0 + n;
    if (node >= NN) node = NN - 1;
    const float4 av = *reinterpret_cast<const float4*>(x + (size_t)node * 64 + k4 * 4);
    float4 yv = *reinterpret_cast<const float4*>(y + (size_t)node * 64 + k4 * 4);
    const float dn = -dinv[node];
    yv.x *= dn; yv.y *= dn; yv.z *= dn; yv.w *= dn;
    float* da = &XA[n][k4 * 4];
    da[0] = av.x; da[1] = av.y; da[2] = av.z; da[3] = av.w;
    float* dy = &XY[n][k4 * 4];
    dy[0] = yv.x; dy[1] = yv.y; dy[2] = yv.z; dy[3] = yv.w;
  }
  __syncthreads();
  const int cw0 = wv * 16;
  const float* __restrict__ W0 = W + cw0;             // [64][128]
  const float* __restrict__ W1 = W + 64 * 128 + cw0;
  float acc[16];
#pragma unroll
  for (int j = 0; j < 16; j++) acc[j] = 0.f;
#pragma unroll 4
  for (int k = 0; k < 64; k++) {
    const float a = XA[lane][k];
    const float b = XY[lane][k];
#pragma unroll
    for (int j = 0; j < 16; j++)
      acc[j] += a * W0[(size_t)k * 128 + j] + b * W1[(size_t)k * 128 + j];
  }
  const int node = n0 + lane;
  if (node < NN) {
#pragma unroll
    for (int j = 0; j < 16; j += 4) {
      float4 o = make_float4(acc[j] + bias[cw0 + j], acc[j + 1] + bias[cw0 + j + 1],
                             acc[j + 2] + bias[cw0 + j + 2], acc[j + 3] + bias[cw0 + j + 3]);
      *reinterpret_cast<float4*>(out + (size_t)node * 128 + cw0 + j) = o;
    }
  }
}

// ---------------------------------------------------------------- dual GEMM: g = bn(h)@Wa + b, p = dinv * (bn(h)@Wb)
template <int Cin>
__global__ __launch_bounds__(512) void k_gemm_dual(const float* __restrict__ h,
                                                   const float* __restrict__ W,
                                                   const float* __restrict__ bias,
                                                   const float* __restrict__ scale,
                                                   const float* __restrict__ shift,
                                                   const float* __restrict__ dinv,
                                                   float* __restrict__ g,
                                                   float* __restrict__ p) {
  __shared__ float XA[64][Cin + 1];
  const int tid = threadIdx.x;
  const int lane = tid & 63;
  const int wv = __builtin_amdgcn_readfirstlane(tid >> 6);  // 0..7
  const int n0 = blockIdx.x * 64;
  constexpr int C4 = Cin / 4;
  for (int idx = tid; idx < 64 * C4; idx += 512) {
    const int n = idx / C4, k4 = idx % C4;
    int node = n0 + n;
    if (node >= NN) node = NN - 1;
    float4 v = *reinterpret_cast<const float4*>(h + (size_t)node * Cin + k4 * 4);
    const float4 sc = *reinterpret_cast<const float4*>(scale + k4 * 4);
    const float4 sh = *reinterpret_cast<const float4*>(shift + k4 * 4);
    v.x = sc.x * v.x + sh.x; v.y = sc.y * v.y + sh.y;
    v.z = sc.z * v.z + sh.z; v.w = sc.w * v.w + sh.w;
    v.x = v.x >= 0.f ? v.x : LRELU_SLOPE * v.x;
    v.y = v.y >= 0.f ? v.y : LRELU_SLOPE * v.y;
    v.z = v.z >= 0.f ? v.z : LRELU_SLOPE * v.z;
    v.w = v.w >= 0.f ? v.w : LRELU_SLOPE * v.w;
    float* d = &XA[n][k4 * 4];
    d[0] = v.x; d[1] = v.y; d[2] = v.z; d[3] = v.w;
  }
  __syncthreads();
  const int cw0 = wv * 8;
  const float* __restrict__ Wa = W + cw0;              // [Cin][64]
  const float* __restrict__ Wb = W + Cin * 64 + cw0;
  float ag[8], ap[8];
#pragma unroll
  for (int j = 0; j < 8; j++) { ag[j] = 0.f; ap[j] = 0.f; }
#pragma unroll 4
  for (int k = 0; k < Cin; k++) {
    const float a = XA[lane][k];
#pragma unroll
    for (int j = 0; j < 8; j++) {
      ag[j] += a * Wa[(size_t)k * 64 + j];
      ap[j] += a * Wb[(size_t)k * 64 + j];
    }
  }
  const int node = n0 + lane;
  if (node < NN) {
    const float dn = dinv[node];
#pragma unroll
    for (int j = 0; j < 8; j += 4) {
      float4 og = make_float4(ag[j] + bias[cw0 + j], ag[j + 1] + bias[cw0 + j + 1],
                              ag[j + 2] + bias[cw0 + j + 2], ag[j + 3] + bias[cw0 + j + 3]);
      *reinterpret_cast<float4*>(g + (size_t)node * 64 + cw0 + j) = og;
      float4 op = make_float4(ap[j] * dn, ap[j + 1] * dn, ap[j + 2] * dn, ap[j + 3] * dn);
      *reinterpret_cast<float4*>(p + (size_t)node * 64 + cw0 + j) = op;
    }
  }
}

// ---------------------------------------------------------------- BN stats (per-channel sum / sumsq)
template <int C>
__global__ __launch_bounds__(256) void k_bnstats(const float* __restrict__ h,
                                                 float* __restrict__ bnsum,
                                                 float* __restrict__ bnsq) {
  constexpr int RPB = 256 / C;
  constexpr int ROWS = 256;
  const int c = threadIdx.x % C;
  const int g = threadIdx.x / C;
  const int r0 = blockIdx.x * ROWS + g;
  const int rend = min(blockIdx.x * ROWS + ROWS, NN);
  float s = 0.f, sq = 0.f;
  for (int r = r0; r < rend; r += RPB) {
    float v = h[(size_t)r * C + c];
    s += v;
    sq += v * v;
  }
  __shared__ float ss[256], sg[256];
  ss[threadIdx.x] = s;
  sg[threadIdx.x] = sq;
  __syncthreads();
  for (int st = 128; st >= C; st >>= 1) {
    if (threadIdx.x < st) {
      ss[threadIdx.x] += ss[threadIdx.x + st];
      sg[threadIdx.x] += sg[threadIdx.x + st];
    }
    __syncthreads();
  }
  if (threadIdx.x < C) {
    atomicAdd(&bnsum[threadIdx.x], ss[threadIdx.x]);
    atomicAdd(&bnsq[threadIdx.x], sg[threadIdx.x]);
  }
}

template <int C>
__global__ void k_bnfin(const float* __restrict__ bnsum, const float* __restrict__ bnsq,
                        const float* __restrict__ gamma, const float* __restrict__ beta,
                        float* __restrict__ scale, float* __restrict__ shift) {
  int c = threadIdx.x;
  if (c < C) {
    float mean = bnsum[c] * (1.0f / NN);
    float var = bnsq[c] * (1.0f / NN) - mean * mean;
    float sc = gamma[c] * rsqrtf(var + BN_EPS);
    scale[c] = sc;
    shift[c] = beta[c] - mean * sc;
  }
}

// ----------------------------------------------------------------
extern "C" void kernel_launch(void* const* d_in, const int* in_sizes, int n_in,
                              void* d_out, int out_size, void* d_ws, size_t ws_size,
                              hipStream_t stream) {
  const float* x   = (const float*)d_in[0];
  const int*   ei  = (const int*)d_in[1];
  const int*   row = ei;
  const int*   col = ei + NE;
  const float* W1  = (const float*)d_in[2];
  const float* b1  = (const float*)d_in[3];
  const float* W2  = (const float*)d_in[4];
  const float* b2  = (const float*)d_in[5];
  const float* W3  = (const float*)d_in[6];
  const float* b3  = (const float*)d_in[7];
  const float* g1  = (const float*)d_in[8];
  const float* be1 = (const float*)d_in[9];
  const float* g2w = (const float*)d_in[10];
  const float* be2 = (const float*)d_in[11];
  float* out = (float*)d_out;

  char* ws = (char*)d_ws;
  size_t off = 0;
  auto alloc = [&](size_t bytes) -> void* {
    void* p = ws + off;
    off = (off + bytes + 255) & ~(size_t)255;
    return p;
  };

  // --- zeroed region (one tiny memset) ---
  float* bnsum1 = (float*)alloc(128 * 4);
  float* bnsq1  = (float*)alloc(128 * 4);
  float* bnsum2 = (float*)alloc(64 * 4);
  float* bnsq2  = (float*)alloc(64 * 4);
  int*   colCnt = (int*)alloc(NR * 4);
  int*   rowCnt = (int*)alloc(NR * 4);
  const size_t zero_bytes = off;
  // --- rest ---
  float* dinv   = (float*)alloc(NN * 4);
  int*   cnt    = (int*)alloc(NN * 4);
  int*   ptr    = (int*)alloc((NN + 1) * 4);
  int*   bsum   = (int*)alloc(SC_NB * 4);
  int*   boff   = (int*)alloc(SC_NB * 4);
  int*   eb     = (int*)alloc((size_t)NE * 4);
  float* scale1 = (float*)alloc(128 * 4);
  float* shift1 = (float*)alloc(128 * 4);
  float* scale2 = (float*)alloc(64 * 4);
  float* shift2 = (float*)alloc(64 * 4);
  float* bufA   = (float*)alloc((size_t)NN * 64 * 4);   // y1, later g2
  float* bufB   = (float*)alloc((size_t)NN * 128 * 4);  // colbuf|rowbuf, then h1, later g3|p3
  float* bufC   = (float*)alloc((size_t)NN * 64 * 4);   // PDc|PDd|Bpart, then xs, later p2
  float* bufD   = (float*)alloc((size_t)NN * 64 * 4);   // h2

  // build scratch aliases
  int2* colbuf = (int2*)bufB;                           // [NR][CAP] 8B  (17.1 MB)
  int*  rowbuf = (int*)(colbuf + (size_t)NR * CAP);     // [NR][CAP] 4B  (8.5 MB)  -> 25.6 <= 51.2 MB
  int*  PDc    = (int*)bufC;                            // [NR][SB][RB]  (3.4 MB)
  int*  PDd    = PDc + (size_t)NR * SB * RB;            // [NR][SB][RB]  (3.4 MB)
  int*  Bpart  = PDd + (size_t)NR * SB * RB;            // [SB][NN]      (3.2 MB)  -> 10.0 <= 25.6 MB

  float* y1  = bufA;
  float* xs  = bufC;
  float* h1  = bufB;
  float* gg2 = bufA;
  float* p2  = bufC;
  float* h2  = bufD;
  float* gg3 = bufB;
  float* p3  = bufB + (size_t)NN * 64;

  hipMemsetAsync(d_ws, 0, zero_bytes, stream);

  // graph prep: two-level bucket counting sort (LDS atomics only on hot path)
  k_part<<<PBLK, 256, 0, stream>>>(row, col, colCnt, rowCnt, colbuf, rowbuf);
  k_hist2<<<dim3(NR, SB, 2), 1024, 0, stream>>>(colbuf, rowbuf, colCnt, rowCnt, PDc, PDd);
  k_csrmid2<<<(NN + 255) / 256, 256, 0, stream>>>(PDc, PDd, Bpart, cnt, dinv);
  k_scan_a<<<SC_NB, 256, 0, stream>>>(cnt, bsum);
  k_scan_b<<<1, 512, 0, stream>>>(bsum, boff);
  k_scan_c<<<SC_NB, 256, 0, stream>>>(cnt, boff, ptr);
  k_fill4<<<dim3(NR, SB), 1024, 0, stream>>>(colbuf, colCnt, ptr, Bpart, eb);

  const int gemmGrid = (NN + 63) / 64;
  const int propGrid = (NN * 16 + 255) / 256;

  // layer 1: xs = dinv*x ; y1 = sum_gather(xs) ; h1 = x@W1[0] + (-dinv*y1)@W1[1] + b1
  k_scale<<<NN * 16 / 256, 256, 0, stream>>>(x, dinv, xs);
  k_prop64<false><<<propGrid, 256, 0, stream>>>(xs, eb, ptr, nullptr, nullptr, y1);
  k_conv1<<<gemmGrid, 512, 0, stream>>>(x, y1, dinv, W1, b1, h1);
  k_bnstats<128><<<(NN + 255) / 256, 256, 0, stream>>>(h1, bnsum1, bnsq1);
  k_bnfin<128><<<1, 128, 0, stream>>>(bnsum1, bnsq1, g1, be1, scale1, shift1);

  // layer 2: g2 = bn(h1)@W2[0]+b2, p2 = dinv*(bn(h1)@W2[1]); h2 = g2 - dinv*sum_gather(p2)
  k_gemm_dual<128><<<gemmGrid, 512, 0, stream>>>(h1, W2, b2, scale1, shift1, dinv, gg2, p2);
  k_prop64<true><<<propGrid, 256, 0, stream>>>(p2, eb, ptr, gg2, dinv, h2);
  k_bnstats<64><<<(NN + 255) / 256, 256, 0, stream>>>(h2, bnsum2, bnsq2);
  k_bnfin<64><<<1, 64, 0, stream>>>(bnsum2, bnsq2, g2w, be2, scale2, shift2);

  // layer 3: g3 = bn(h2)@W3[0]+b3, p3 = dinv*(bn(h2)@W3[1]); out = g3 - dinv*sum_gather(p3)
  k_gemm_dual<64><<<gemmGrid, 512, 0, stream>>>(h2, W3, b3, scale2, shift2, dinv, gg3, p3);
  k_prop64<true><<<propGrid, 256, 0, stream>>>(p3, eb, ptr, gg3, dinv, out);
}

// Round 8
// 573.918 us; speedup vs baseline: 1.4254x; 1.0143x over previous
//
#include <hip/hip_runtime.h>

#define NN 100000
#define NE 1600000
constexpr float BN_EPS = 1e-5f;
constexpr float LRELU_SLOPE = 0.01f;
constexpr int SC_NB = (NN + 255) / 256;  // 391 scan blocks
constexpr int RSH = 13;                  // range shift (8192)
constexpr int RB = 1 << RSH;             // 8192 nodes per range-bucket
constexpr int NR = (NN + RB - 1) / RB;   // 13 buckets
constexpr int SB = 8;                    // slices per bucket (phase 2/4)
constexpr int CAP = 163840;              // bucket capacity (mean 131k, sigma ~350)
constexpr int PBLK = 400;                // partition blocks
constexpr int PCHUNK = NE / PBLK;        // 4000 edges per partition block

// ---------------------------------------------------------------- P1: partition edges by col-range / row-range
// colbuf record packs (src<<13)|(col&8191) in one int; rowbuf stores 13-bit offsets as ushort.
__global__ __launch_bounds__(256) void k_part(const int* __restrict__ row,
                                              const int* __restrict__ col,
                                              int* __restrict__ colCnt,   // [NR] zeroed
                                              int* __restrict__ rowCnt,   // [NR] zeroed
                                              int* __restrict__ colbuf,   // [NR][CAP]
                                              unsigned short* __restrict__ rowbuf) {
  __shared__ int cntc[NR], cntr[NR];
  const int tid = threadIdx.x;
  const int e0 = blockIdx.x * PCHUNK;
  if (tid < NR) { cntc[tid] = 0; cntr[tid] = 0; }
  __syncthreads();
  for (int i = tid; i < PCHUNK; i += 256) {
    atomicAdd(&cntc[col[e0 + i] >> RSH], 1);
    atomicAdd(&cntr[row[e0 + i] >> RSH], 1);
  }
  __syncthreads();
  if (tid < NR) {
    cntc[tid] = atomicAdd(&colCnt[tid], cntc[tid]);            // base in col-bucket
  } else if (tid >= 64 && tid < 64 + NR) {
    const int b = tid - 64;
    cntr[b] = atomicAdd(&rowCnt[b], cntr[b]);                  // base in row-bucket
  }
  __syncthreads();
  for (int i = tid; i < PCHUNK; i += 256) {
    const int r = row[e0 + i];
    const int c = col[e0 + i];
    const int bc = c >> RSH;
    const int pc = atomicAdd(&cntc[bc], 1);
    colbuf[(size_t)bc * CAP + pc] = (r << RSH) | (c & (RB - 1));
    const int br = r >> RSH;
    const int pr = atomicAdd(&cntr[br], 1);
    rowbuf[(size_t)br * CAP + pr] = (unsigned short)(r & (RB - 1));
  }
}

// ---------------------------------------------------------------- P2: per-(bucket,slice) LDS histogram
__global__ __launch_bounds__(1024) void k_hist2(const int* __restrict__ colbuf,
                                                const unsigned short* __restrict__ rowbuf,
                                                const int* __restrict__ colCnt,
                                                const int* __restrict__ rowCnt,
                                                int* __restrict__ PDc,   // [NR][SB][RB]
                                                int* __restrict__ PDd) { // [NR][SB][RB]
  __shared__ int h[RB];
  const int tid = threadIdx.x;
  const int b = blockIdx.x, s = blockIdx.y, z = blockIdx.z;
  for (int i = tid; i < RB; i += 1024) h[i] = 0;
  __syncthreads();
  const int len = z ? rowCnt[b] : colCnt[b];
  const int sl = (len + SB - 1) / SB;
  const int st = s * sl;
  const int en = min(st + sl, len);
  if (z == 0) {
    const int* cb = colbuf + (size_t)b * CAP;
    for (int i = st + tid; i < en; i += 1024)
      atomicAdd(&h[cb[i] & (RB - 1)], 1);
  } else {
    const unsigned short* rb = rowbuf + (size_t)b * CAP;
    for (int i = st + tid; i < en; i += 1024)
      atomicAdd(&h[rb[i]], 1);
  }
  __syncthreads();
  int* pd = (z ? PDd : PDc) + ((size_t)b * SB + s) * RB;
  for (int i = tid; i < RB; i += 1024) pd[i] = h[i];
}

// ---------------------------------------------------------------- P3: per-node slice prefix + totals + dinv
__global__ __launch_bounds__(256) void k_csrmid2(const int* __restrict__ PDc,
                                                 const int* __restrict__ PDd,
                                                 int* __restrict__ Bpart,  // [SB][NN]
                                                 int* __restrict__ cnt,
                                                 float* __restrict__ dinv) {
  const int n = blockIdx.x * 256 + threadIdx.x;
  if (n >= NN) return;
  const int b = n >> RSH, o = n & (RB - 1);
  int run = 0, dsum = 0;
#pragma unroll
  for (int s = 0; s < SB; s++) {
    Bpart[(size_t)s * NN + n] = run;
    run += PDc[((size_t)b * SB + s) * RB + o];
    dsum += PDd[((size_t)b * SB + s) * RB + o];
  }
  cnt[n] = run;
  dinv[n] = dsum > 0 ? rsqrtf((float)dsum) : 0.0f;
}

// ---------------------------------------------------------------- 3-phase exclusive scan of cnt
__global__ __launch_bounds__(256) void k_scan_a(const int* __restrict__ cnt,
                                                int* __restrict__ bsum) {
  __shared__ int sh[256];
  const int tid = threadIdx.x;
  const int i = blockIdx.x * 256 + tid;
  sh[tid] = (i < NN) ? cnt[i] : 0;
  __syncthreads();
  for (int st = 128; st > 0; st >>= 1) {
    if (tid < st) sh[tid] += sh[tid + st];
    __syncthreads();
  }
  if (tid == 0) bsum[blockIdx.x] = sh[0];
}

__global__ __launch_bounds__(512) void k_scan_b(const int* __restrict__ bsum,
                                                int* __restrict__ boff) {
  __shared__ int sh[512];
  const int tid = threadIdx.x;
  const int v = (tid < SC_NB) ? bsum[tid] : 0;
  sh[tid] = v;
  __syncthreads();
  for (int off = 1; off < 512; off <<= 1) {
    int t = (tid >= off) ? sh[tid - off] : 0;
    __syncthreads();
    sh[tid] += t;
    __syncthreads();
  }
  if (tid < SC_NB) boff[tid] = sh[tid] - v;  // exclusive
}

__global__ __launch_bounds__(256) void k_scan_c(const int* __restrict__ cnt,
                                                const int* __restrict__ boff,
                                                int* __restrict__ ptr) {
  __shared__ int sh[256];
  const int tid = threadIdx.x;
  const int i = blockIdx.x * 256 + tid;
  const int v = (i < NN) ? cnt[i] : 0;
  sh[tid] = v;
  __syncthreads();
  for (int off = 1; off < 256; off <<= 1) {
    int t = (tid >= off) ? sh[tid - off] : 0;
    __syncthreads();
    sh[tid] += t;
    __syncthreads();
  }
  const int excl = sh[tid] - v + boff[blockIdx.x];
  if (i < NN) {
    ptr[i] = excl;
    if (i == NN - 1) ptr[NN] = excl + v;
  }
}

// ---------------------------------------------------------------- P4: place edges via LDS cursors
__global__ __launch_bounds__(1024) void k_fill4(const int* __restrict__ colbuf,
                                                const int* __restrict__ colCnt,
                                                const int* __restrict__ ptr,
                                                const int* __restrict__ Bpart,
                                                int* __restrict__ eb) {
  __shared__ int cur[RB];
  const int tid = threadIdx.x;
  const int b = blockIdx.x, s = blockIdx.y;
  const int base = b << RSH;
  const int nmax = min(RB, NN - base);
  const int* bp = Bpart + (size_t)s * NN + base;
  for (int i = tid; i < nmax; i += 1024) cur[i] = ptr[base + i] + bp[i];
  __syncthreads();
  const int len = colCnt[b];
  const int sl = (len + SB - 1) / SB;
  const int st = s * sl;
  const int en = min(st + sl, len);
  const int* cb = colbuf + (size_t)b * CAP;
  for (int i = st + tid; i < en; i += 1024) {
    const int rec = cb[i];
    const int pos = atomicAdd(&cur[rec & (RB - 1)], 1);
    eb[pos] = rec >> RSH;
  }
}

// ---------------------------------------------------------------- xs = dinv * x (layer-1 pre-scale)
__global__ __launch_bounds__(256) void k_scale(const float* __restrict__ x,
                                               const float* __restrict__ dinv,
                                               float* __restrict__ xs) {
  const size_t i = (size_t)blockIdx.x * 256 + threadIdx.x;  // float4 index, grid exact
  const int n = (int)(i >> 4);
  float4 v = reinterpret_cast<const float4*>(x)[i];
  const float d = dinv[n];
  v.x *= d; v.y *= d; v.z *= d; v.w *= d;
  reinterpret_cast<float4*>(xs)[i] = v;
}

// ---------------------------------------------------------------- prop: acc[n] = sum_{e: col=n} p[src_e]
template <bool ADD>
__global__ __launch_bounds__(256) void k_prop64(const float* __restrict__ p,
                                                const int* __restrict__ eb,
                                                const int* __restrict__ ptr,
                                                const float* __restrict__ g,
                                                const float* __restrict__ dinv,
                                                float* __restrict__ out) {
  const int node = blockIdx.x * 16 + (threadIdx.x >> 4);
  const int lane = threadIdx.x & 15;
  if (node >= NN) return;
  const int b = ptr[node], e = ptr[node + 1];
  float4 a0 = make_float4(0.f, 0.f, 0.f, 0.f);
  float4 a1 = make_float4(0.f, 0.f, 0.f, 0.f);
  float4 a2 = make_float4(0.f, 0.f, 0.f, 0.f);
  float4 a3 = make_float4(0.f, 0.f, 0.f, 0.f);
  const float4* hp = reinterpret_cast<const float4*>(p) + lane;
  int j = b;
  for (; j + 4 <= e; j += 4) {
    const int s0 = eb[j], s1 = eb[j + 1], s2 = eb[j + 2], s3 = eb[j + 3];
    const float4 h0 = hp[(size_t)s0 * 16];
    const float4 h1 = hp[(size_t)s1 * 16];
    const float4 h2 = hp[(size_t)s2 * 16];
    const float4 h3 = hp[(size_t)s3 * 16];
    a0.x += h0.x; a0.y += h0.y; a0.z += h0.z; a0.w += h0.w;
    a1.x += h1.x; a1.y += h1.y; a1.z += h1.z; a1.w += h1.w;
    a2.x += h2.x; a2.y += h2.y; a2.z += h2.z; a2.w += h2.w;
    a3.x += h3.x; a3.y += h3.y; a3.z += h3.z; a3.w += h3.w;
  }
  for (; j + 2 <= e; j += 2) {
    const int s0 = eb[j], s1 = eb[j + 1];
    const float4 h0 = hp[(size_t)s0 * 16];
    const float4 h1 = hp[(size_t)s1 * 16];
    a0.x += h0.x; a0.y += h0.y; a0.z += h0.z; a0.w += h0.w;
    a1.x += h1.x; a1.y += h1.y; a1.z += h1.z; a1.w += h1.w;
  }
  if (j < e) {
    const float4 h0 = hp[(size_t)eb[j] * 16];
    a0.x += h0.x; a0.y += h0.y; a0.z += h0.z; a0.w += h0.w;
  }
  a0.x += a1.x + a2.x + a3.x;
  a0.y += a1.y + a2.y + a3.y;
  a0.z += a1.z + a2.z + a3.z;
  a0.w += a1.w + a2.w + a3.w;
  if (ADD) {
    const float dn = dinv[node];
    const float4 gv = reinterpret_cast<const float4*>(g)[(size_t)node * 16 + lane];
    a0.x = gv.x - dn * a0.x;
    a0.y = gv.y - dn * a0.y;
    a0.z = gv.z - dn * a0.z;
    a0.w = gv.w - dn * a0.w;
  }
  reinterpret_cast<float4*>(out)[(size_t)node * 16 + lane] = a0;
}

// ---------------------------------------------------------------- layer-1 conv: h1 = x@W0 + (-dinv*y)@W1 + b
// 128 nodes/block, 2 nodes/thread: same scalar W loads feed 2x FMAs.
__global__ __launch_bounds__(512) void k_conv1(const float* __restrict__ x,
                                               const float* __restrict__ y,
                                               const float* __restrict__ dinv,
                                               const float* __restrict__ W,
                                               const float* __restrict__ bias,
                                               float* __restrict__ out) {
  __shared__ float XA[128][65];
  __shared__ float XY[128][65];
  const int tid = threadIdx.x;
  const int lane = tid & 63;
  const int wv = __builtin_amdgcn_readfirstlane(tid >> 6);  // 0..7
  const int n0 = blockIdx.x * 128;
  for (int idx = tid; idx < 2048; idx += 512) {
    const int n = idx >> 4, k4 = idx & 15;
    int node = n0 + n;
    if (node >= NN) node = NN - 1;
    const float4 av = *reinterpret_cast<const float4*>(x + (size_t)node * 64 + k4 * 4);
    float4 yv = *reinterpret_cast<const float4*>(y + (size_t)node * 64 + k4 * 4);
    const float dn = -dinv[node];
    yv.x *= dn; yv.y *= dn; yv.z *= dn; yv.w *= dn;
    float* da = &XA[n][k4 * 4];
    da[0] = av.x; da[1] = av.y; da[2] = av.z; da[3] = av.w;
    float* dy = &XY[n][k4 * 4];
    dy[0] = yv.x; dy[1] = yv.y; dy[2] = yv.z; dy[3] = yv.w;
  }
  __syncthreads();
  const int cw0 = wv * 16;
  const float* __restrict__ W0 = W + cw0;             // [64][128]
  const float* __restrict__ W1 = W + 64 * 128 + cw0;
  float acc0[16], acc1[16];
#pragma unroll
  for (int j = 0; j < 16; j++) { acc0[j] = 0.f; acc1[j] = 0.f; }
#pragma unroll 2
  for (int k = 0; k < 64; k++) {
    const float a0 = XA[lane][k];
    const float a1 = XA[lane + 64][k];
    const float b0 = XY[lane][k];
    const float b1 = XY[lane + 64][k];
#pragma unroll
    for (int j = 0; j < 16; j++) {
      const float w0 = W0[(size_t)k * 128 + j];
      const float w1 = W1[(size_t)k * 128 + j];
      acc0[j] += a0 * w0 + b0 * w1;
      acc1[j] += a1 * w0 + b1 * w1;
    }
  }
#pragma unroll
  for (int half = 0; half < 2; half++) {
    const int node = n0 + lane + half * 64;
    const float* acc = half ? acc1 : acc0;
    if (node < NN) {
#pragma unroll
      for (int j = 0; j < 16; j += 4) {
        float4 o = make_float4(acc[j] + bias[cw0 + j], acc[j + 1] + bias[cw0 + j + 1],
                               acc[j + 2] + bias[cw0 + j + 2], acc[j + 3] + bias[cw0 + j + 3]);
        *reinterpret_cast<float4*>(out + (size_t)node * 128 + cw0 + j) = o;
      }
    }
  }
}

// ---------------------------------------------------------------- dual GEMM: g = bn(h)@Wa + b, p = dinv * (bn(h)@Wb)
// 128 nodes/block, 2 nodes/thread.
template <int Cin>
__global__ __launch_bounds__(512) void k_gemm_dual(const float* __restrict__ h,
                                                   const float* __restrict__ W,
                                                   const float* __restrict__ bias,
                                                   const float* __restrict__ scale,
                                                   const float* __restrict__ shift,
                                                   const float* __restrict__ dinv,
                                                   float* __restrict__ g,
                                                   float* __restrict__ p) {
  __shared__ float XA[128][Cin + 1];
  const int tid = threadIdx.x;
  const int lane = tid & 63;
  const int wv = __builtin_amdgcn_readfirstlane(tid >> 6);  // 0..7
  const int n0 = blockIdx.x * 128;
  constexpr int C4 = Cin / 4;
  for (int idx = tid; idx < 128 * C4; idx += 512) {
    const int n = idx / C4, k4 = idx % C4;
    int node = n0 + n;
    if (node >= NN) node = NN - 1;
    float4 v = *reinterpret_cast<const float4*>(h + (size_t)node * Cin + k4 * 4);
    const float4 sc = *reinterpret_cast<const float4*>(scale + k4 * 4);
    const float4 sh = *reinterpret_cast<const float4*>(shift + k4 * 4);
    v.x = sc.x * v.x + sh.x; v.y = sc.y * v.y + sh.y;
    v.z = sc.z * v.z + sh.z; v.w = sc.w * v.w + sh.w;
    v.x = v.x >= 0.f ? v.x : LRELU_SLOPE * v.x;
    v.y = v.y >= 0.f ? v.y : LRELU_SLOPE * v.y;
    v.z = v.z >= 0.f ? v.z : LRELU_SLOPE * v.z;
    v.w = v.w >= 0.f ? v.w : LRELU_SLOPE * v.w;
    float* d = &XA[n][k4 * 4];
    d[0] = v.x; d[1] = v.y; d[2] = v.z; d[3] = v.w;
  }
  __syncthreads();
  const int cw0 = wv * 8;
  const float* __restrict__ Wa = W + cw0;              // [Cin][64]
  const float* __restrict__ Wb = W + Cin * 64 + cw0;
  float ag0[8], ag1[8], ap0[8], ap1[8];
#pragma unroll
  for (int j = 0; j < 8; j++) { ag0[j] = 0.f; ag1[j] = 0.f; ap0[j] = 0.f; ap1[j] = 0.f; }
#pragma unroll 2
  for (int k = 0; k < Cin; k++) {
    const float a0 = XA[lane][k];
    const float a1 = XA[lane + 64][k];
#pragma unroll
    for (int j = 0; j < 8; j++) {
      const float wa = Wa[(size_t)k * 64 + j];
      const float wb = Wb[(size_t)k * 64 + j];
      ag0[j] += a0 * wa; ag1[j] += a1 * wa;
      ap0[j] += a0 * wb; ap1[j] += a1 * wb;
    }
  }
#pragma unroll
  for (int half = 0; half < 2; half++) {
    const int node = n0 + lane + half * 64;
    const float* ag = half ? ag1 : ag0;
    const float* ap = half ? ap1 : ap0;
    if (node < NN) {
      const float dn = dinv[node];
#pragma unroll
      for (int j = 0; j < 8; j += 4) {
        float4 og = make_float4(ag[j] + bias[cw0 + j], ag[j + 1] + bias[cw0 + j + 1],
                                ag[j + 2] + bias[cw0 + j + 2], ag[j + 3] + bias[cw0 + j + 3]);
        *reinterpret_cast<float4*>(g + (size_t)node * 64 + cw0 + j) = og;
        float4 op = make_float4(ap[j] * dn, ap[j + 1] * dn, ap[j + 2] * dn, ap[j + 3] * dn);
        *reinterpret_cast<float4*>(p + (size_t)node * 64 + cw0 + j) = op;
      }
    }
  }
}

// ---------------------------------------------------------------- BN stats (per-channel sum / sumsq)
template <int C>
__global__ __launch_bounds__(256) void k_bnstats(const float* __restrict__ h,
                                                 float* __restrict__ bnsum,
                                                 float* __restrict__ bnsq) {
  constexpr int RPB = 256 / C;
  constexpr int ROWS = 256;
  const int c = threadIdx.x % C;
  const int g = threadIdx.x / C;
  const int r0 = blockIdx.x * ROWS + g;
  const int rend = min(blockIdx.x * ROWS + ROWS, NN);
  float s = 0.f, sq = 0.f;
  for (int r = r0; r < rend; r += RPB) {
    float v = h[(size_t)r * C + c];
    s += v;
    sq += v * v;
  }
  __shared__ float ss[256], sg[256];
  ss[threadIdx.x] = s;
  sg[threadIdx.x] = sq;
  __syncthreads();
  for (int st = 128; st >= C; st >>= 1) {
    if (threadIdx.x < st) {
      ss[threadIdx.x] += ss[threadIdx.x + st];
      sg[threadIdx.x] += sg[threadIdx.x + st];
    }
    __syncthreads();
  }
  if (threadIdx.x < C) {
    atomicAdd(&bnsum[threadIdx.x], ss[threadIdx.x]);
    atomicAdd(&bnsq[threadIdx.x], sg[threadIdx.x]);
  }
}

template <int C>
__global__ void k_bnfin(const float* __restrict__ bnsum, const float* __restrict__ bnsq,
                        const float* __restrict__ gamma, const float* __restrict__ beta,
                        float* __restrict__ scale, float* __restrict__ shift) {
  int c = threadIdx.x;
  if (c < C) {
    float mean = bnsum[c] * (1.0f / NN);
    float var = bnsq[c] * (1.0f / NN) - mean * mean;
    float sc = gamma[c] * rsqrtf(var + BN_EPS);
    scale[c] = sc;
    shift[c] = beta[c] - mean * sc;
  }
}

// ----------------------------------------------------------------
extern "C" void kernel_launch(void* const* d_in, const int* in_sizes, int n_in,
                              void* d_out, int out_size, void* d_ws, size_t ws_size,
                              hipStream_t stream) {
  const float* x   = (const float*)d_in[0];
  const int*   ei  = (const int*)d_in[1];
  const int*   row = ei;
  const int*   col = ei + NE;
  const float* W1  = (const float*)d_in[2];
  const float* b1  = (const float*)d_in[3];
  const float* W2  = (const float*)d_in[4];
  const float* b2  = (const float*)d_in[5];
  const float* W3  = (const float*)d_in[6];
  const float* b3  = (const float*)d_in[7];
  const float* g1  = (const float*)d_in[8];
  const float* be1 = (const float*)d_in[9];
  const float* g2w = (const float*)d_in[10];
  const float* be2 = (const float*)d_in[11];
  float* out = (float*)d_out;

  char* ws = (char*)d_ws;
  size_t off = 0;
  auto alloc = [&](size_t bytes) -> void* {
    void* p = ws + off;
    off = (off + bytes + 255) & ~(size_t)255;
    return p;
  };

  // --- zeroed region (one tiny memset) ---
  float* bnsum1 = (float*)alloc(128 * 4);
  float* bnsq1  = (float*)alloc(128 * 4);
  float* bnsum2 = (float*)alloc(64 * 4);
  float* bnsq2  = (float*)alloc(64 * 4);
  int*   colCnt = (int*)alloc(NR * 4);
  int*   rowCnt = (int*)alloc(NR * 4);
  const size_t zero_bytes = off;
  // --- rest ---
  float* dinv   = (float*)alloc(NN * 4);
  int*   cnt    = (int*)alloc(NN * 4);
  int*   ptr    = (int*)alloc((NN + 1) * 4);
  int*   bsum   = (int*)alloc(SC_NB * 4);
  int*   boff   = (int*)alloc(SC_NB * 4);
  int*   eb     = (int*)alloc((size_t)NE * 4);
  float* scale1 = (float*)alloc(128 * 4);
  float* shift1 = (float*)alloc(128 * 4);
  float* scale2 = (float*)alloc(64 * 4);
  float* shift2 = (float*)alloc(64 * 4);
  float* bufA   = (float*)alloc((size_t)NN * 64 * 4);   // y1, later g2
  float* bufB   = (float*)alloc((size_t)NN * 128 * 4);  // colbuf|rowbuf, then h1, later g3|p3
  float* bufC   = (float*)alloc((size_t)NN * 64 * 4);   // PDc|PDd|Bpart, then xs, later p2
  float* bufD   = (float*)alloc((size_t)NN * 64 * 4);   // h2

  // build scratch aliases
  int* colbuf = (int*)bufB;                                   // [NR][CAP] 4B (8.5 MB)
  unsigned short* rowbuf = (unsigned short*)(colbuf + (size_t)NR * CAP);  // [NR][CAP] 2B (4.3 MB)
  int* PDc    = (int*)bufC;                                   // [NR][SB][RB]  (3.4 MB)
  int* PDd    = PDc + (size_t)NR * SB * RB;                   // [NR][SB][RB]  (3.4 MB)
  int* Bpart  = PDd + (size_t)NR * SB * RB;                   // [SB][NN]      (3.2 MB)

  float* y1  = bufA;
  float* xs  = bufC;
  float* h1  = bufB;
  float* gg2 = bufA;
  float* p2  = bufC;
  float* h2  = bufD;
  float* gg3 = bufB;
  float* p3  = bufB + (size_t)NN * 64;

  hipMemsetAsync(d_ws, 0, zero_bytes, stream);

  // graph prep: two-level bucket counting sort (LDS atomics only on hot path)
  k_part<<<PBLK, 256, 0, stream>>>(row, col, colCnt, rowCnt, colbuf, rowbuf);
  k_hist2<<<dim3(NR, SB, 2), 1024, 0, stream>>>(colbuf, rowbuf, colCnt, rowCnt, PDc, PDd);
  k_csrmid2<<<(NN + 255) / 256, 256, 0, stream>>>(PDc, PDd, Bpart, cnt, dinv);
  k_scan_a<<<SC_NB, 256, 0, stream>>>(cnt, bsum);
  k_scan_b<<<1, 512, 0, stream>>>(bsum, boff);
  k_scan_c<<<SC_NB, 256, 0, stream>>>(cnt, boff, ptr);
  k_fill4<<<dim3(NR, SB), 1024, 0, stream>>>(colbuf, colCnt, ptr, Bpart, eb);

  const int gemmGrid = (NN + 127) / 128;
  const int propGrid = (NN * 16 + 255) / 256;

  // layer 1: xs = dinv*x ; y1 = sum_gather(xs) ; h1 = x@W1[0] + (-dinv*y1)@W1[1] + b1
  k_scale<<<NN * 16 / 256, 256, 0, stream>>>(x, dinv, xs);
  k_prop64<false><<<propGrid, 256, 0, stream>>>(xs, eb, ptr, nullptr, nullptr, y1);
  k_conv1<<<gemmGrid, 512, 0, stream>>>(x, y1, dinv, W1, b1, h1);
  k_bnstats<128><<<(NN + 255) / 256, 256, 0, stream>>>(h1, bnsum1, bnsq1);
  k_bnfin<128><<<1, 128, 0, stream>>>(bnsum1, bnsq1, g1, be1, scale1, shift1);

  // layer 2: g2 = bn(h1)@W2[0]+b2, p2 = dinv*(bn(h1)@W2[1]); h2 = g2 - dinv*sum_gather(p2)
  k_gemm_dual<128><<<gemmGrid, 512, 0, stream>>>(h1, W2, b2, scale1, shift1, dinv, gg2, p2);
  k_prop64<true><<<propGrid, 256, 0, stream>>>(p2, eb, ptr, gg2, dinv, h2);
  k_bnstats<64><<<(NN + 255) / 256, 256, 0, stream>>>(h2, bnsum2, bnsq2);
  k_bnfin<64><<<1, 64, 0, stream>>>(bnsum2, bnsq2, g2w, be2, scale2, shift2);

  // layer 3: g3 = bn(h2)@W3[0]+b3, p3 = dinv*(bn(h2)@W3[1]); out = g3 - dinv*sum_gather(p3)
  k_gemm_dual<64><<<gemmGrid, 512, 0, stream>>>(h2, W3, b3, scale2, shift2, dinv, gg3, p3);
  k_prop64<true><<<propGrid, 256, 0, stream>>>(p3, eb, ptr, gg3, dinv, out);
}

// Round 9
// 565.992 us; speedup vs baseline: 1.4454x; 1.0140x over previous
//
#include <hip/hip_runtime.h>

#define NN 100000
#define NE 1600000
constexpr float BN_EPS = 1e-5f;
constexpr float LRELU_SLOPE = 0.01f;
constexpr int SC_NB = (NN + 255) / 256;  // 391 scan blocks
constexpr int RSH = 13;                  // range shift (8192)
constexpr int RB = 1 << RSH;             // 8192 nodes per range-bucket
constexpr int NR = (NN + RB - 1) / RB;   // 13 buckets
constexpr int SB = 8;                    // slices per bucket (phase 2/4)
constexpr int CAP = 163840;              // bucket capacity
constexpr int PBLK = 400;                // partition blocks
constexpr int PCHUNK = NE / PBLK;        // 4000 edges per partition block

// ---------------------------------------------------------------- P1: partition edges by col-range / row-range
__global__ __launch_bounds__(256) void k_part(const int* __restrict__ row,
                                              const int* __restrict__ col,
                                              int* __restrict__ colCnt,
                                              int* __restrict__ rowCnt,
                                              int* __restrict__ colbuf,
                                              unsigned short* __restrict__ rowbuf) {
  __shared__ int cntc[NR], cntr[NR];
  const int tid = threadIdx.x;
  const int e0 = blockIdx.x * PCHUNK;
  if (tid < NR) { cntc[tid] = 0; cntr[tid] = 0; }
  __syncthreads();
  for (int i = tid; i < PCHUNK; i += 256) {
    atomicAdd(&cntc[col[e0 + i] >> RSH], 1);
    atomicAdd(&cntr[row[e0 + i] >> RSH], 1);
  }
  __syncthreads();
  if (tid < NR) {
    cntc[tid] = atomicAdd(&colCnt[tid], cntc[tid]);
  } else if (tid >= 64 && tid < 64 + NR) {
    const int b = tid - 64;
    cntr[b] = atomicAdd(&rowCnt[b], cntr[b]);
  }
  __syncthreads();
  for (int i = tid; i < PCHUNK; i += 256) {
    const int r = row[e0 + i];
    const int c = col[e0 + i];
    const int bc = c >> RSH;
    const int pc = atomicAdd(&cntc[bc], 1);
    colbuf[(size_t)bc * CAP + pc] = (r << RSH) | (c & (RB - 1));
    const int br = r >> RSH;
    const int pr = atomicAdd(&cntr[br], 1);
    rowbuf[(size_t)br * CAP + pr] = (unsigned short)(r & (RB - 1));
  }
}

// ---------------------------------------------------------------- P2: per-(bucket,slice) LDS histogram
__global__ __launch_bounds__(1024) void k_hist2(const int* __restrict__ colbuf,
                                                const unsigned short* __restrict__ rowbuf,
                                                const int* __restrict__ colCnt,
                                                const int* __restrict__ rowCnt,
                                                int* __restrict__ PDc,
                                                int* __restrict__ PDd) {
  __shared__ int h[RB];
  const int tid = threadIdx.x;
  const int b = blockIdx.x, s = blockIdx.y, z = blockIdx.z;
  for (int i = tid; i < RB; i += 1024) h[i] = 0;
  __syncthreads();
  const int len = z ? rowCnt[b] : colCnt[b];
  const int sl = (len + SB - 1) / SB;
  const int st = s * sl;
  const int en = min(st + sl, len);
  if (z == 0) {
    const int* cb = colbuf + (size_t)b * CAP;
    for (int i = st + tid; i < en; i += 1024)
      atomicAdd(&h[cb[i] & (RB - 1)], 1);
  } else {
    const unsigned short* rb = rowbuf + (size_t)b * CAP;
    for (int i = st + tid; i < en; i += 1024)
      atomicAdd(&h[rb[i]], 1);
  }
  __syncthreads();
  int* pd = (z ? PDd : PDc) + ((size_t)b * SB + s) * RB;
  for (int i = tid; i < RB; i += 1024) pd[i] = h[i];
}

// ---------------------------------------------------------------- P3: per-node slice prefix + totals + dinv
__global__ __launch_bounds__(256) void k_csrmid2(const int* __restrict__ PDc,
                                                 const int* __restrict__ PDd,
                                                 int* __restrict__ Bpart,
                                                 int* __restrict__ cnt,
                                                 float* __restrict__ dinv) {
  const int n = blockIdx.x * 256 + threadIdx.x;
  if (n >= NN) return;
  const int b = n >> RSH, o = n & (RB - 1);
  int run = 0, dsum = 0;
#pragma unroll
  for (int s = 0; s < SB; s++) {
    Bpart[(size_t)s * NN + n] = run;
    run += PDc[((size_t)b * SB + s) * RB + o];
    dsum += PDd[((size_t)b * SB + s) * RB + o];
  }
  cnt[n] = run;
  dinv[n] = dsum > 0 ? rsqrtf((float)dsum) : 0.0f;
}

// ---------------------------------------------------------------- 3-phase exclusive scan of cnt
__global__ __launch_bounds__(256) void k_scan_a(const int* __restrict__ cnt,
                                                int* __restrict__ bsum) {
  __shared__ int sh[256];
  const int tid = threadIdx.x;
  const int i = blockIdx.x * 256 + tid;
  sh[tid] = (i < NN) ? cnt[i] : 0;
  __syncthreads();
  for (int st = 128; st > 0; st >>= 1) {
    if (tid < st) sh[tid] += sh[tid + st];
    __syncthreads();
  }
  if (tid == 0) bsum[blockIdx.x] = sh[0];
}

__global__ __launch_bounds__(512) void k_scan_b(const int* __restrict__ bsum,
                                                int* __restrict__ boff) {
  __shared__ int sh[512];
  const int tid = threadIdx.x;
  const int v = (tid < SC_NB) ? bsum[tid] : 0;
  sh[tid] = v;
  __syncthreads();
  for (int off = 1; off < 512; off <<= 1) {
    int t = (tid >= off) ? sh[tid - off] : 0;
    __syncthreads();
    sh[tid] += t;
    __syncthreads();
  }
  if (tid < SC_NB) boff[tid] = sh[tid] - v;  // exclusive
}

__global__ __launch_bounds__(256) void k_scan_c(const int* __restrict__ cnt,
                                                const int* __restrict__ boff,
                                                int* __restrict__ ptr) {
  __shared__ int sh[256];
  const int tid = threadIdx.x;
  const int i = blockIdx.x * 256 + tid;
  const int v = (i < NN) ? cnt[i] : 0;
  sh[tid] = v;
  __syncthreads();
  for (int off = 1; off < 256; off <<= 1) {
    int t = (tid >= off) ? sh[tid - off] : 0;
    __syncthreads();
    sh[tid] += t;
    __syncthreads();
  }
  const int excl = sh[tid] - v + boff[blockIdx.x];
  if (i < NN) {
    ptr[i] = excl;
    if (i == NN - 1) ptr[NN] = excl + v;
  }
}

// ---------------------------------------------------------------- P4: place edges via LDS cursors
__global__ __launch_bounds__(1024) void k_fill4(const int* __restrict__ colbuf,
                                                const int* __restrict__ colCnt,
                                                const int* __restrict__ ptr,
                                                const int* __restrict__ Bpart,
                                                int* __restrict__ eb) {
  __shared__ int cur[RB];
  const int tid = threadIdx.x;
  const int b = blockIdx.x, s = blockIdx.y;
  const int base = b << RSH;
  const int nmax = min(RB, NN - base);
  const int* bp = Bpart + (size_t)s * NN + base;
  for (int i = tid; i < nmax; i += 1024) cur[i] = ptr[base + i] + bp[i];
  __syncthreads();
  const int len = colCnt[b];
  const int sl = (len + SB - 1) / SB;
  const int st = s * sl;
  const int en = min(st + sl, len);
  const int* cb = colbuf + (size_t)b * CAP;
  for (int i = st + tid; i < en; i += 1024) {
    const int rec = cb[i];
    const int pos = atomicAdd(&cur[rec & (RB - 1)], 1);
    eb[pos] = rec >> RSH;
  }
}

// ---------------------------------------------------------------- prop: acc[n] = sum_{e: col=n} [dinv[s]*] p[src_e]
// SCALE: gather dinv[s]*p[s] (layer-1, fuses the old k_scale). ADD: out = g - dinv[n]*acc.
template <bool SCALE, bool ADD>
__global__ __launch_bounds__(256) void k_prop64(const float* __restrict__ p,
                                                const int* __restrict__ eb,
                                                const int* __restrict__ ptr,
                                                const float* __restrict__ g,
                                                const float* __restrict__ dinv,
                                                float* __restrict__ out) {
  const int node = blockIdx.x * 16 + (threadIdx.x >> 4);
  const int lane = threadIdx.x & 15;
  if (node >= NN) return;
  const int b = ptr[node], e = ptr[node + 1];
  float4 a0 = make_float4(0.f, 0.f, 0.f, 0.f);
  float4 a1 = make_float4(0.f, 0.f, 0.f, 0.f);
  float4 a2 = make_float4(0.f, 0.f, 0.f, 0.f);
  float4 a3 = make_float4(0.f, 0.f, 0.f, 0.f);
  const float4* hp = reinterpret_cast<const float4*>(p) + lane;
  int j = b;
  for (; j + 4 <= e; j += 4) {
    const int s0 = eb[j], s1 = eb[j + 1], s2 = eb[j + 2], s3 = eb[j + 3];
    const float w0 = SCALE ? dinv[s0] : 1.f;
    const float w1 = SCALE ? dinv[s1] : 1.f;
    const float w2 = SCALE ? dinv[s2] : 1.f;
    const float w3 = SCALE ? dinv[s3] : 1.f;
    const float4 h0 = hp[(size_t)s0 * 16];
    const float4 h1 = hp[(size_t)s1 * 16];
    const float4 h2 = hp[(size_t)s2 * 16];
    const float4 h3 = hp[(size_t)s3 * 16];
    if (SCALE) {
      a0.x += w0 * h0.x; a0.y += w0 * h0.y; a0.z += w0 * h0.z; a0.w += w0 * h0.w;
      a1.x += w1 * h1.x; a1.y += w1 * h1.y; a1.z += w1 * h1.z; a1.w += w1 * h1.w;
      a2.x += w2 * h2.x; a2.y += w2 * h2.y; a2.z += w2 * h2.z; a2.w += w2 * h2.w;
      a3.x += w3 * h3.x; a3.y += w3 * h3.y; a3.z += w3 * h3.z; a3.w += w3 * h3.w;
    } else {
      a0.x += h0.x; a0.y += h0.y; a0.z += h0.z; a0.w += h0.w;
      a1.x += h1.x; a1.y += h1.y; a1.z += h1.z; a1.w += h1.w;
      a2.x += h2.x; a2.y += h2.y; a2.z += h2.z; a2.w += h2.w;
      a3.x += h3.x; a3.y += h3.y; a3.z += h3.z; a3.w += h3.w;
    }
  }
  for (; j < e; j++) {
    const int s0 = eb[j];
    const float w0 = SCALE ? dinv[s0] : 1.f;
    const float4 h0 = hp[(size_t)s0 * 16];
    if (SCALE) {
      a0.x += w0 * h0.x; a0.y += w0 * h0.y; a0.z += w0 * h0.z; a0.w += w0 * h0.w;
    } else {
      a0.x += h0.x; a0.y += h0.y; a0.z += h0.z; a0.w += h0.w;
    }
  }
  a0.x += a1.x + a2.x + a3.x;
  a0.y += a1.y + a2.y + a3.y;
  a0.z += a1.z + a2.z + a3.z;
  a0.w += a1.w + a2.w + a3.w;
  if (ADD) {
    const float dn = dinv[node];
    const float4 gv = reinterpret_cast<const float4*>(g)[(size_t)node * 16 + lane];
    a0.x = gv.x - dn * a0.x;
    a0.y = gv.y - dn * a0.y;
    a0.z = gv.z - dn * a0.z;
    a0.w = gv.w - dn * a0.w;
  }
  reinterpret_cast<float4*>(out)[(size_t)node * 16 + lane] = a0;
}

// ---------------------------------------------------------------- layer-1 conv: h1 = x@W0 + (-dinv*y)@W1 + b
// 64 nodes/block, 1 node/thread, XA/XY stride 68 (16B-aligned): ds_read_b64 per 2 k,
// W rows via s_load (SGPR FMA operand). Chunked reads batch the lgkm waits.
__global__ __launch_bounds__(512) void k_conv1(const float* __restrict__ x,
                                               const float* __restrict__ y,
                                               const float* __restrict__ dinv,
                                               const float* __restrict__ W,
                                               const float* __restrict__ bias,
                                               float* __restrict__ out) {
  constexpr int LDW = 68;
  __shared__ float XA[64][LDW];
  __shared__ float XY[64][LDW];
  const int tid = threadIdx.x;
  const int lane = tid & 63;
  const int wv = __builtin_amdgcn_readfirstlane(tid >> 6);  // 0..7
  const int n0 = blockIdx.x * 64;
  for (int idx = tid; idx < 1024; idx += 512) {
    const int n = idx >> 4, k4 = idx & 15;
    int node = n0 + n;
    if (node >= NN) node = NN - 1;
    const float4 av = *reinterpret_cast<const float4*>(x + (size_t)node * 64 + k4 * 4);
    float4 yv = *reinterpret_cast<const float4*>(y + (size_t)node * 64 + k4 * 4);
    const float dn = -dinv[node];
    yv.x *= dn; yv.y *= dn; yv.z *= dn; yv.w *= dn;
    *reinterpret_cast<float4*>(&XA[n][k4 * 4]) = av;
    *reinterpret_cast<float4*>(&XY[n][k4 * 4]) = yv;
  }
  __syncthreads();
  const int cw0 = wv * 16;
  const float* __restrict__ W0 = W + cw0;             // [64][128]
  const float* __restrict__ W1 = W + 64 * 128 + cw0;
  float acc[16];
#pragma unroll
  for (int j = 0; j < 16; j++) acc[j] = 0.f;
#pragma unroll 2
  for (int kc = 0; kc < 32; kc++) {
    const float2 a2 = *reinterpret_cast<const float2*>(&XA[lane][kc * 2]);
    const float2 y2 = *reinterpret_cast<const float2*>(&XY[lane][kc * 2]);
    const int k0 = kc * 2;
#pragma unroll
    for (int j = 0; j < 16; j++)
      acc[j] += a2.x * W0[(size_t)k0 * 128 + j] + y2.x * W1[(size_t)k0 * 128 + j];
#pragma unroll
    for (int j = 0; j < 16; j++)
      acc[j] += a2.y * W0[(size_t)(k0 + 1) * 128 + j] + y2.y * W1[(size_t)(k0 + 1) * 128 + j];
  }
  const int node = n0 + lane;
  if (node < NN) {
#pragma unroll
    for (int j = 0; j < 16; j += 4) {
      float4 o = make_float4(acc[j] + bias[cw0 + j], acc[j + 1] + bias[cw0 + j + 1],
                             acc[j + 2] + bias[cw0 + j + 2], acc[j + 3] + bias[cw0 + j + 3]);
      *reinterpret_cast<float4*>(out + (size_t)node * 128 + cw0 + j) = o;
    }
  }
}

// ---------------------------------------------------------------- dual GEMM: g = bn(h)@Wa + b, p = dinv * (bn(h)@Wb)
// 64 nodes/block, 1 node/thread, XA stride Cin+4 (16B-aligned): ds_read_b128 per 4 k.
template <int Cin>
__global__ __launch_bounds__(512) void k_gemm_dual(const float* __restrict__ h,
                                                   const float* __restrict__ W,
                                                   const float* __restrict__ bias,
                                                   const float* __restrict__ scale,
                                                   const float* __restrict__ shift,
                                                   const float* __restrict__ dinv,
                                                   float* __restrict__ g,
                                                   float* __restrict__ p) {
  constexpr int LDW = Cin + 4;
  __shared__ float XA[64][LDW];
  const int tid = threadIdx.x;
  const int lane = tid & 63;
  const int wv = __builtin_amdgcn_readfirstlane(tid >> 6);  // 0..7
  const int n0 = blockIdx.x * 64;
  constexpr int C4 = Cin / 4;
  for (int idx = tid; idx < 64 * C4; idx += 512) {
    const int n = idx / C4, k4 = idx % C4;
    int node = n0 + n;
    if (node >= NN) node = NN - 1;
    float4 v = *reinterpret_cast<const float4*>(h + (size_t)node * Cin + k4 * 4);
    const float4 sc = *reinterpret_cast<const float4*>(scale + k4 * 4);
    const float4 sh = *reinterpret_cast<const float4*>(shift + k4 * 4);
    v.x = sc.x * v.x + sh.x; v.y = sc.y * v.y + sh.y;
    v.z = sc.z * v.z + sh.z; v.w = sc.w * v.w + sh.w;
    v.x = v.x >= 0.f ? v.x : LRELU_SLOPE * v.x;
    v.y = v.y >= 0.f ? v.y : LRELU_SLOPE * v.y;
    v.z = v.z >= 0.f ? v.z : LRELU_SLOPE * v.z;
    v.w = v.w >= 0.f ? v.w : LRELU_SLOPE * v.w;
    *reinterpret_cast<float4*>(&XA[n][k4 * 4]) = v;
  }
  __syncthreads();
  const int cw0 = wv * 8;
  const float* __restrict__ Wa = W + cw0;              // [Cin][64]
  const float* __restrict__ Wb = W + Cin * 64 + cw0;
  float ag[8], ap[8];
#pragma unroll
  for (int j = 0; j < 8; j++) { ag[j] = 0.f; ap[j] = 0.f; }
#pragma unroll 2
  for (int kc = 0; kc < C4; kc++) {
    const float4 a4 = *reinterpret_cast<const float4*>(&XA[lane][kc * 4]);
    const int k0 = kc * 4;
#pragma unroll
    for (int j = 0; j < 8; j++) {
      ag[j] += a4.x * Wa[(size_t)k0 * 64 + j];
      ap[j] += a4.x * Wb[(size_t)k0 * 64 + j];
    }
#pragma unroll
    for (int j = 0; j < 8; j++) {
      ag[j] += a4.y * Wa[(size_t)(k0 + 1) * 64 + j];
      ap[j] += a4.y * Wb[(size_t)(k0 + 1) * 64 + j];
    }
#pragma unroll
    for (int j = 0; j < 8; j++) {
      ag[j] += a4.z * Wa[(size_t)(k0 + 2) * 64 + j];
      ap[j] += a4.z * Wb[(size_t)(k0 + 2) * 64 + j];
    }
#pragma unroll
    for (int j = 0; j < 8; j++) {
      ag[j] += a4.w * Wa[(size_t)(k0 + 3) * 64 + j];
      ap[j] += a4.w * Wb[(size_t)(k0 + 3) * 64 + j];
    }
  }
  const int node = n0 + lane;
  if (node < NN) {
    const float dn = dinv[node];
#pragma unroll
    for (int j = 0; j < 8; j += 4) {
      float4 og = make_float4(ag[j] + bias[cw0 + j], ag[j + 1] + bias[cw0 + j + 1],
                              ag[j + 2] + bias[cw0 + j + 2], ag[j + 3] + bias[cw0 + j + 3]);
      *reinterpret_cast<float4*>(g + (size_t)node * 64 + cw0 + j) = og;
      float4 op = make_float4(ap[j] * dn, ap[j + 1] * dn, ap[j + 2] * dn, ap[j + 3] * dn);
      *reinterpret_cast<float4*>(p + (size_t)node * 64 + cw0 + j) = op;
    }
  }
}

// ---------------------------------------------------------------- BN stats (per-channel sum / sumsq)
template <int C>
__global__ __launch_bounds__(256) void k_bnstats(const float* __restrict__ h,
                                                 float* __restrict__ bnsum,
                                                 float* __restrict__ bnsq) {
  constexpr int RPB = 256 / C;
  constexpr int ROWS = 256;
  const int c = threadIdx.x % C;
  const int g = threadIdx.x / C;
  const int r0 = blockIdx.x * ROWS + g;
  const int rend = min(blockIdx.x * ROWS + ROWS, NN);
  float s = 0.f, sq = 0.f;
  for (int r = r0; r < rend; r += RPB) {
    float v = h[(size_t)r * C + c];
    s += v;
    sq += v * v;
  }
  __shared__ float ss[256], sg[256];
  ss[threadIdx.x] = s;
  sg[threadIdx.x] = sq;
  __syncthreads();
  for (int st = 128; st >= C; st >>= 1) {
    if (threadIdx.x < st) {
      ss[threadIdx.x] += ss[threadIdx.x + st];
      sg[threadIdx.x] += sg[threadIdx.x + st];
    }
    __syncthreads();
  }
  if (threadIdx.x < C) {
    atomicAdd(&bnsum[threadIdx.x], ss[threadIdx.x]);
    atomicAdd(&bnsq[threadIdx.x], sg[threadIdx.x]);
  }
}

template <int C>
__global__ void k_bnfin(const float* __restrict__ bnsum, const float* __restrict__ bnsq,
                        const float* __restrict__ gamma, const float* __restrict__ beta,
                        float* __restrict__ scale, float* __restrict__ shift) {
  int c = threadIdx.x;
  if (c < C) {
    float mean = bnsum[c] * (1.0f / NN);
    float var = bnsq[c] * (1.0f / NN) - mean * mean;
    float sc = gamma[c] * rsqrtf(var + BN_EPS);
    scale[c] = sc;
    shift[c] = beta[c] - mean * sc;
  }
}

// ----------------------------------------------------------------
extern "C" void kernel_launch(void* const* d_in, const int* in_sizes, int n_in,
                              void* d_out, int out_size, void* d_ws, size_t ws_size,
                              hipStream_t stream) {
  const float* x   = (const float*)d_in[0];
  const int*   ei  = (const int*)d_in[1];
  const int*   row = ei;
  const int*   col = ei + NE;
  const float* W1  = (const float*)d_in[2];
  const float* b1  = (const float*)d_in[3];
  const float* W2  = (const float*)d_in[4];
  const float* b2  = (const float*)d_in[5];
  const float* W3  = (const float*)d_in[6];
  const float* b3  = (const float*)d_in[7];
  const float* g1  = (const float*)d_in[8];
  const float* be1 = (const float*)d_in[9];
  const float* g2w = (const float*)d_in[10];
  const float* be2 = (const float*)d_in[11];
  float* out = (float*)d_out;

  char* ws = (char*)d_ws;
  size_t off = 0;
  auto alloc = [&](size_t bytes) -> void* {
    void* p = ws + off;
    off = (off + bytes + 255) & ~(size_t)255;
    return p;
  };

  // --- zeroed region (one tiny memset) ---
  float* bnsum1 = (float*)alloc(128 * 4);
  float* bnsq1  = (float*)alloc(128 * 4);
  float* bnsum2 = (float*)alloc(64 * 4);
  float* bnsq2  = (float*)alloc(64 * 4);
  int*   colCnt = (int*)alloc(NR * 4);
  int*   rowCnt = (int*)alloc(NR * 4);
  const size_t zero_bytes = off;
  // --- rest ---
  float* dinv   = (float*)alloc(NN * 4);
  int*   cnt    = (int*)alloc(NN * 4);
  int*   ptr    = (int*)alloc((NN + 1) * 4);
  int*   bsum   = (int*)alloc(SC_NB * 4);
  int*   boff   = (int*)alloc(SC_NB * 4);
  int*   eb     = (int*)alloc((size_t)NE * 4);
  float* scale1 = (float*)alloc(128 * 4);
  float* shift1 = (float*)alloc(128 * 4);
  float* scale2 = (float*)alloc(64 * 4);
  float* shift2 = (float*)alloc(64 * 4);
  float* bufA   = (float*)alloc((size_t)NN * 64 * 4);   // y1, later g2
  float* bufB   = (float*)alloc((size_t)NN * 128 * 4);  // colbuf|rowbuf, then h1, later g3|p3
  float* bufC   = (float*)alloc((size_t)NN * 64 * 4);   // PDc|PDd|Bpart, later p2
  float* bufD   = (float*)alloc((size_t)NN * 64 * 4);   // h2

  // build scratch aliases
  int* colbuf = (int*)bufB;                                   // [NR][CAP] 4B
  unsigned short* rowbuf = (unsigned short*)(colbuf + (size_t)NR * CAP);  // [NR][CAP] 2B
  int* PDc    = (int*)bufC;                                   // [NR][SB][RB]
  int* PDd    = PDc + (size_t)NR * SB * RB;                   // [NR][SB][RB]
  int* Bpart  = PDd + (size_t)NR * SB * RB;                   // [SB][NN]

  float* y1  = bufA;
  float* h1  = bufB;
  float* gg2 = bufA;
  float* p2  = bufC;
  float* h2  = bufD;
  float* gg3 = bufB;
  float* p3  = bufB + (size_t)NN * 64;

  hipMemsetAsync(d_ws, 0, zero_bytes, stream);

  // graph prep: two-level bucket counting sort (LDS atomics only on hot path)
  k_part<<<PBLK, 256, 0, stream>>>(row, col, colCnt, rowCnt, colbuf, rowbuf);
  k_hist2<<<dim3(NR, SB, 2), 1024, 0, stream>>>(colbuf, rowbuf, colCnt, rowCnt, PDc, PDd);
  k_csrmid2<<<(NN + 255) / 256, 256, 0, stream>>>(PDc, PDd, Bpart, cnt, dinv);
  k_scan_a<<<SC_NB, 256, 0, stream>>>(cnt, bsum);
  k_scan_b<<<1, 512, 0, stream>>>(bsum, boff);
  k_scan_c<<<SC_NB, 256, 0, stream>>>(cnt, boff, ptr);
  k_fill4<<<dim3(NR, SB), 1024, 0, stream>>>(colbuf, colCnt, ptr, Bpart, eb);

  const int gemmGrid = (NN + 63) / 64;
  const int propGrid = (NN * 16 + 255) / 256;

  // layer 1: y1 = sum dinv[s]*x[s] (scale fused); h1 = x@W1[0] + (-dinv*y1)@W1[1] + b1
  k_prop64<true, false><<<propGrid, 256, 0, stream>>>(x, eb, ptr, nullptr, dinv, y1);
  k_conv1<<<gemmGrid, 512, 0, stream>>>(x, y1, dinv, W1, b1, h1);
  k_bnstats<128><<<(NN + 255) / 256, 256, 0, stream>>>(h1, bnsum1, bnsq1);
  k_bnfin<128><<<1, 128, 0, stream>>>(bnsum1, bnsq1, g1, be1, scale1, shift1);

  // layer 2: g2 = bn(h1)@W2[0]+b2, p2 = dinv*(bn(h1)@W2[1]); h2 = g2 - dinv*sum_gather(p2)
  k_gemm_dual<128><<<gemmGrid, 512, 0, stream>>>(h1, W2, b2, scale1, shift1, dinv, gg2, p2);
  k_prop64<false, true><<<propGrid, 256, 0, stream>>>(p2, eb, ptr, gg2, dinv, h2);
  k_bnstats<64><<<(NN + 255) / 256, 256, 0, stream>>>(h2, bnsum2, bnsq2);
  k_bnfin<64><<<1, 64, 0, stream>>>(bnsum2, bnsq2, g2w, be2, scale2, shift2);

  // layer 3: g3 = bn(h2)@W3[0]+b3, p3 = dinv*(bn(h2)@W3[1]); out = g3 - dinv*sum_gather(p3)
  k_gemm_dual<64><<<gemmGrid, 512, 0, stream>>>(h2, W3, b3, scale2, shift2, dinv, gg3, p3);
  k_prop64<false, true><<<propGrid, 256, 0, stream>>>(p3, eb, ptr, gg3, dinv, out);
}